// Round 9
// baseline (313.215 us; speedup 1.0000x reference)
//
#include <hip/hip_runtime.h>
#include <hip/hip_bf16.h>

// Problem constants
#define NB 128     // batch
#define AA 128     // conv1 out channels
#define BB 32      // capsule types
#define CC 10      // classes
#define KK 6       // primary grid
#define DD 16      // pose dim
#define NN 1152    // B*K*K
#define H1 14      // conv1 out spatial
#define CH2 544    // B*D+B
#define NG 4608    // GEMM N = NB*36
#define KG 1152    // GEMM K = 128*9
#define MG 576     // GEMM M padded (544 -> 3*192)

typedef short bfrag8 __attribute__((ext_vector_type(8)));   // 8 bf16 (4 VGPRs)
typedef float facc4 __attribute__((ext_vector_type(4)));    // 4 fp32 acc

__device__ __forceinline__ unsigned short f2bf(float f) {   // RNE f32->bf16
    unsigned u = __float_as_uint(f);
    u += 0x7FFF + ((u >> 16) & 1);
    return (unsigned short)(u >> 16);
}
__device__ __forceinline__ float bf2f(unsigned short s) {
    return __uint_as_float(((unsigned)s) << 16);
}

// ---------------- conv1 (LDS-staged): (128,3,32,32) -> (128,128,14,14), 5x5 s2 --------
__global__ __launch_bounds__(256, 3) void k_conv1(const float* __restrict__ x,
                                                  const float* __restrict__ w,
                                                  float* __restrict__ h) {
    __shared__ __align__(16) float sX[3][7][32];   //  2,688 B
    __shared__ float sWf[AA * 75];                 // 38,400 B
    const int p = blockIdx.x;
    const int b = blockIdx.y;
    const int tid = threadIdx.x;
    for (int j = tid; j < AA * 75; j += 256) sWf[j] = w[j];
    for (int j = tid; j < 3 * 7 * 32; j += 256) {
        int col = j & 31; int t2 = j >> 5; int row = t2 % 7; int ic = t2 / 7;
        sX[ic][row][col] = x[b * 3072 + ic * 1024 + (4 * p + row) * 32 + col];
    }
    __syncthreads();
    const int oc = tid & 127, ry = tid >> 7;
    const int r = 2 * p + ry;
    float acc[14];
#pragma unroll
    for (int j = 0; j < 14; ++j) acc[j] = 0.f;
    const float* wr = sWf + oc * 75;
#pragma unroll
    for (int ic = 0; ic < 3; ++ic) {
#pragma unroll
        for (int ky = 0; ky < 5; ++ky) {
            const float* xr = &sX[ic][2 * ry + ky][0];
            float row[32];
#pragma unroll
            for (int q = 0; q < 8; ++q) {
                float4 v = *reinterpret_cast<const float4*>(xr + q * 4);
                row[q * 4 + 0] = v.x; row[q * 4 + 1] = v.y;
                row[q * 4 + 2] = v.z; row[q * 4 + 3] = v.w;
            }
            float w0 = wr[ic * 25 + ky * 5 + 0];
            float w1 = wr[ic * 25 + ky * 5 + 1];
            float w2 = wr[ic * 25 + ky * 5 + 2];
            float w3 = wr[ic * 25 + ky * 5 + 3];
            float w4 = wr[ic * 25 + ky * 5 + 4];
#pragma unroll
            for (int ox = 0; ox < 14; ++ox) {
                float s = acc[ox];
                s = fmaf(row[2 * ox + 0], w0, s);
                s = fmaf(row[2 * ox + 1], w1, s);
                s = fmaf(row[2 * ox + 2], w2, s);
                s = fmaf(row[2 * ox + 3], w3, s);
                s = fmaf(row[2 * ox + 4], w4, s);
                acc[ox] = s;
            }
        }
    }
    float* out = h + ((size_t)(b * AA + oc) * 14 + r) * 14;
#pragma unroll
    for (int q = 0; q < 7; ++q)
        *reinterpret_cast<float2*>(out + q * 2) = make_float2(acc[q * 2], acc[q * 2 + 1]);
}

// ---------------- bn1 stats: per-channel mean/var over (b, 14, 14) ----------------
__global__ void k_bnstats1(const float* __restrict__ h, const float* __restrict__ g,
                           const float* __restrict__ be, float* __restrict__ bn1) {
    int c = blockIdx.x;
    int tid = threadIdx.x;
    float s = 0.f, s2 = 0.f;
    for (int j = tid; j < NB * 196; j += 256) {
        int b = j / 196, hw = j % 196;
        float v = h[(b * AA + c) * 196 + hw];
        s += v; s2 += v * v;
    }
#pragma unroll
    for (int o = 32; o > 0; o >>= 1) { s += __shfl_down(s, o); s2 += __shfl_down(s2, o); }
    __shared__ float ls[4], lq[4];
    int lane = tid & 63, wid = tid >> 6;
    if (lane == 0) { ls[wid] = s; lq[wid] = s2; }
    __syncthreads();
    if (tid == 0) {
        s = ls[0] + ls[1] + ls[2] + ls[3];
        s2 = lq[0] + lq[1] + lq[2] + lq[3];
        const float n = (float)(NB * 196);
        float mu = s / n;
        float var = s2 / n - mu * mu;
        float sc = g[c] * rsqrtf(var + 1e-5f);
        bn1[c] = sc;
        bn1[AA + c] = be[c] - mu * sc;
    }
}

// ---------------- prep weights: prim_w [544][1152] f32 -> Ah/Al [576][1152] bf16 ------
__global__ void k_prepw(const float* __restrict__ w, unsigned short* __restrict__ Ah,
                        unsigned short* __restrict__ Al) {
    int t = blockIdx.x * 256 + threadIdx.x;
    if (t >= MG * (KG / 8)) return;
    int row = t / (KG / 8), seg = t % (KG / 8);
    alignas(16) unsigned short hi[8], lo[8];
    if (row < CH2) {
        const float* src = w + (size_t)row * KG + seg * 8;
#pragma unroll
        for (int j = 0; j < 8; ++j) {
            float v = src[j];
            unsigned short hh = f2bf(v);
            hi[j] = hh;
            lo[j] = f2bf(v - bf2f(hh));
        }
    } else {
#pragma unroll
        for (int j = 0; j < 8; ++j) { hi[j] = 0; lo[j] = 0; }
    }
    *reinterpret_cast<uint4*>(Ah + (size_t)row * KG + seg * 8) = *reinterpret_cast<const uint4*>(hi);
    *reinterpret_cast<uint4*>(Al + (size_t)row * KG + seg * 8) = *reinterpret_cast<const uint4*>(lo);
}

// ---------------- conv2: fused im2col + split-bf16 MFMA GEMM ----------------
// pcT[n][oc] = sum_k A[oc][k] * B[n][k],  B built on the fly from h (+bn1+relu).
// grid (3, 72): M-tile 192, N-tile 64. 256 threads = 4 waves (2M x 2N).
// Pipelined: gathers for step ks+1 issue before COMPUTE(ks).
__global__ __launch_bounds__(256) void k_gemm(const unsigned short* __restrict__ Ah,
                                              const unsigned short* __restrict__ Al,
                                              const float* __restrict__ h,
                                              const float* __restrict__ bn1,
                                              float* __restrict__ pcT) {
    __shared__ alignas(16) unsigned short sAh[192][44], sAl[192][44];  // 33,792 B
    __shared__ alignas(16) unsigned short sBh[64][44],  sBl[64][44];   // 11,264 B
    __shared__ float sBn[2 * AA];                                      //  1,024 B
    const int m0 = blockIdx.x * 192;
    const int n0 = blockIdx.y * 64;
    const int tid = threadIdx.x;
    const int lane = tid & 63, wv = tid >> 6;
    const int wm = wv >> 1, wn = wv & 1;
    const int quad = lane >> 4, r16 = lane & 15;

    // A staging slots (constant per thread): 3 x (row, seg)
    int arow[3], aseg[3];
#pragma unroll
    for (int j = 0; j < 3; ++j) { int s = tid + 256 * j; arow[j] = s >> 2; aseg[j] = s & 3; }
    // B staging slot: thread -> (nn, koct)
    const int nn = tid >> 2, koct = tid & 3;
    const int nglob = n0 + nn;
    const int bb = nglob / 36, xy = nglob % 36;
    const int oy = xy / 6, ox = xy % 6;
    const float* hbase = h + (size_t)bb * (AA * 196) + (2 * oy) * 14 + 2 * ox;

    if (tid < 2 * AA) sBn[tid] = bn1[tid];

    uint4 vAh[3], vAl[3];
    float raw[8];

    // LOAD(0)
#pragma unroll
    for (int j = 0; j < 3; ++j) {
        size_t off = (size_t)(m0 + arow[j]) * KG + aseg[j] * 8;
        vAh[j] = *reinterpret_cast<const uint4*>(Ah + off);
        vAl[j] = *reinterpret_cast<const uint4*>(Al + off);
    }
#pragma unroll
    for (int j = 0; j < 8; ++j) {
        int k = koct * 8 + j;
        int ic = k / 9, r9 = k - ic * 9;
        int ky = r9 / 3, kx = r9 - ky * 3;
        raw[j] = hbase[ic * 196 + ky * 14 + kx];
    }

    facc4 acc[6][2] = {};

#pragma unroll 1
    for (int ks = 0; ks < KG / 32; ++ks) {
        __syncthreads();   // previous compute done reading LDS (and sBn ready on iter 0)
        // WRITE(ks): stage regs -> LDS
#pragma unroll
        for (int j = 0; j < 3; ++j) {
            *reinterpret_cast<uint4*>(&sAh[arow[j]][aseg[j] * 8]) = vAh[j];
            *reinterpret_cast<uint4*>(&sAl[arow[j]][aseg[j] * 8]) = vAl[j];
        }
        {
            alignas(16) unsigned short hi8[8], lo8[8];
            const int kb = ks * 32 + koct * 8;
#pragma unroll
            for (int j = 0; j < 8; ++j) {
                int k = kb + j;
                int ic = k / 9;
                float v = fmaf(raw[j], sBn[ic], sBn[AA + ic]);
                v = fmaxf(v, 0.f);
                unsigned short hh = f2bf(v);
                hi8[j] = hh;
                lo8[j] = f2bf(v - bf2f(hh));
            }
            *reinterpret_cast<uint4*>(&sBh[nn][koct * 8]) = *reinterpret_cast<const uint4*>(hi8);
            *reinterpret_cast<uint4*>(&sBl[nn][koct * 8]) = *reinterpret_cast<const uint4*>(lo8);
        }
        __syncthreads();
        // LOAD(ks+1): issue early, lands during compute
        if (ks + 1 < KG / 32) {
            const int k0n = (ks + 1) * 32;
#pragma unroll
            for (int j = 0; j < 3; ++j) {
                size_t off = (size_t)(m0 + arow[j]) * KG + k0n + aseg[j] * 8;
                vAh[j] = *reinterpret_cast<const uint4*>(Ah + off);
                vAl[j] = *reinterpret_cast<const uint4*>(Al + off);
            }
#pragma unroll
            for (int j = 0; j < 8; ++j) {
                int k = k0n + koct * 8 + j;
                int ic = k / 9, r9 = k - ic * 9;
                int ky = r9 / 3, kx = r9 - ky * 3;
                raw[j] = hbase[ic * 196 + ky * 14 + kx];
            }
        }
        // COMPUTE(ks)
        bfrag8 bhf[2], blf[2];
#pragma unroll
        for (int ni = 0; ni < 2; ++ni) {
            bhf[ni] = *reinterpret_cast<const bfrag8*>(&sBh[wn * 32 + ni * 16 + r16][quad * 8]);
            blf[ni] = *reinterpret_cast<const bfrag8*>(&sBl[wn * 32 + ni * 16 + r16][quad * 8]);
        }
#pragma unroll
        for (int mi = 0; mi < 6; ++mi) {
            bfrag8 ah = *reinterpret_cast<const bfrag8*>(&sAh[wm * 96 + mi * 16 + r16][quad * 8]);
            bfrag8 al = *reinterpret_cast<const bfrag8*>(&sAl[wm * 96 + mi * 16 + r16][quad * 8]);
#pragma unroll
            for (int ni = 0; ni < 2; ++ni) {
                acc[mi][ni] = __builtin_amdgcn_mfma_f32_16x16x32_bf16(ah, bhf[ni], acc[mi][ni], 0, 0, 0);
                acc[mi][ni] = __builtin_amdgcn_mfma_f32_16x16x32_bf16(ah, blf[ni], acc[mi][ni], 0, 0, 0);
                acc[mi][ni] = __builtin_amdgcn_mfma_f32_16x16x32_bf16(al, bhf[ni], acc[mi][ni], 0, 0, 0);
            }
        }
    }
    // D mapping: col = lane&15 -> n, row = quad*4+reg -> oc (contiguous float4 in oc)
#pragma unroll
    for (int mi = 0; mi < 6; ++mi) {
        int oc_base = m0 + wm * 96 + mi * 16 + quad * 4;
        if (oc_base >= CH2) continue;
#pragma unroll
        for (int ni = 0; ni < 2; ++ni) {
            int n = n0 + wn * 32 + ni * 16 + r16;
            *reinterpret_cast<facc4*>(pcT + (size_t)n * CH2 + oc_base) = acc[mi][ni];
        }
    }
}

// ---------------- bn stats on pcT[n][oc] ----------------
__global__ void k_bnstats2(const float* __restrict__ pcT,
                           const float* __restrict__ bna_g, const float* __restrict__ bna_b,
                           const float* __restrict__ bnp_g, const float* __restrict__ bnp_b,
                           float* __restrict__ bn2) {
    int blk = blockIdx.x;
    int tid = threadIdx.x;
    float s = 0.f, s2 = 0.f;
    if (blk < 32) {
        int i = blk;
        for (int j = tid; j < NG * 4; j += 256) {
            int row = j >> 2, q = j & 3;
            float4 v = *reinterpret_cast<const float4*>(pcT + (size_t)row * CH2 + i * 16 + q * 4);
            s += v.x + v.y + v.z + v.w;
            s2 += v.x * v.x + v.y * v.y + v.z * v.z + v.w * v.w;
        }
    } else {
        int i = blk - 32;
        for (int j = tid; j < NG; j += 256) {
            float v = pcT[(size_t)j * CH2 + BB * DD + i];
            s += v; s2 += v * v;
        }
    }
#pragma unroll
    for (int o = 32; o > 0; o >>= 1) { s += __shfl_down(s, o); s2 += __shfl_down(s2, o); }
    __shared__ float ls[4], lq[4];
    int lane = tid & 63, wid = tid >> 6;
    if (lane == 0) { ls[wid] = s; lq[wid] = s2; }
    __syncthreads();
    if (tid == 0) {
        s = ls[0] + ls[1] + ls[2] + ls[3];
        s2 = lq[0] + lq[1] + lq[2] + lq[3];
        if (blk < 32) {
            int i = blk;
            const float n = (float)(NB * DD * 36);
            float mu = s / n, var = s2 / n - mu * mu;
            float sc = bnp_g[i] * rsqrtf(var + 1e-5f);
            bn2[i] = sc; bn2[32 + i] = bnp_b[i] - mu * sc;
        } else {
            int i = blk - 32;
            const float n = (float)(NB * 36);
            float mu = s / n, var = s2 / n - mu * mu;
            float sc = bna_g[i] * rsqrtf(var + 1e-5f);
            bn2[64 + i] = sc; bn2[96 + i] = bna_b[i] - mu * sc;
        }
    }
}

// ---------------- transform: pcT -> poses_bn (b,n,16) and a_i (b,n) ----------------
__global__ void k_transform(const float* __restrict__ pcT, const float* __restrict__ bn2,
                            float* __restrict__ pose, float* __restrict__ ai) {
    int idx = blockIdx.x * 256 + threadIdx.x;
    if (idx >= NB * NN) return;
    int b = idx / NN, n = idx % NN;
    int i = n / 36, xy = n % 36;
    int row = b * 36 + xy;
    float sc = bn2[i], sh = bn2[32 + i];
    const float* src = pcT + (size_t)row * CH2 + i * 16;
    float* pd = pose + (size_t)idx * 16;
#pragma unroll
    for (int q = 0; q < 4; ++q) {
        float4 v = *reinterpret_cast<const float4*>(src + q * 4);
        v.x = fmaf(v.x, sc, sh); v.y = fmaf(v.y, sc, sh);
        v.z = fmaf(v.z, sc, sh); v.w = fmaf(v.w, sc, sh);
        *reinterpret_cast<float4*>(pd + q * 4) = v;
    }
    float va = fmaf(pcT[(size_t)row * CH2 + BB * DD + i], bn2[64 + i], bn2[96 + i]);
    ai[idx] = 1.f / (1.f + expf(-va));
}

// ---------------- VB stats: one wave per (b,c) ----------------
template <int FIRST>
__global__ void k_stats(const float* __restrict__ pose, const float* __restrict__ ai,
                        const float* __restrict__ R, const float* __restrict__ Wij,
                        float* __restrict__ Nj, float* __restrict__ S1, float* __restrict__ S2) {
    int bc = blockIdx.x * 4 + (threadIdx.x >> 6);
    int lane = threadIdx.x & 63;
    int c = bc % CC, b = bc / CC;
    float s0 = 0.f;
    float s1[16], s2[16];
#pragma unroll
    for (int k = 0; k < 16; ++k) { s1[k] = 0.f; s2[k] = 0.f; }
    for (int n = lane; n < NN; n += 64) {
        int i = n / 36, xy = n % 36;
        const float4* pp = reinterpret_cast<const float4*>(pose + ((size_t)b * NN + n) * 16);
        const float4* wp = reinterpret_cast<const float4*>(Wij + (((size_t)i * CC + c) * 36 + xy) * 16);
        alignas(16) float P[16], W[16];
        *reinterpret_cast<float4*>(&P[0])  = pp[0];
        *reinterpret_cast<float4*>(&P[4])  = pp[1];
        *reinterpret_cast<float4*>(&P[8])  = pp[2];
        *reinterpret_cast<float4*>(&P[12]) = pp[3];
        *reinterpret_cast<float4*>(&W[0])  = wp[0];
        *reinterpret_cast<float4*>(&W[4])  = wp[1];
        *reinterpret_cast<float4*>(&W[8])  = wp[2];
        *reinterpret_cast<float4*>(&W[12]) = wp[3];
        float wgt = ai[b * NN + n];
        if (FIRST) wgt *= 0.1f;
        else wgt *= R[((size_t)(b * CC + c)) * NN + n];
        s0 += wgt;
#pragma unroll
        for (int p = 0; p < 4; ++p) {
#pragma unroll
            for (int r = 0; r < 4; ++r) {
                float v = W[p * 4 + 0] * P[0 + r] + W[p * 4 + 1] * P[4 + r] +
                          W[p * 4 + 2] * P[8 + r] + W[p * 4 + 3] * P[12 + r];
                int d = p * 4 + r;
                float wv = wgt * v;
                s1[d] += wv;
                s2[d] = fmaf(wv, v, s2[d]);
            }
        }
    }
#pragma unroll
    for (int o = 32; o > 0; o >>= 1) {
        s0 += __shfl_down(s0, o);
#pragma unroll
        for (int k = 0; k < 16; ++k) {
            s1[k] += __shfl_down(s1[k], o);
            s2[k] += __shfl_down(s2[k], o);
        }
    }
    if (lane == 0) {
        Nj[bc] = s0 + 1e-8f;
#pragma unroll
        for (int k = 0; k < 16; ++k) { S1[bc * 16 + k] = s1[k]; S2[bc * 16 + k] = s2[k]; }
    }
}

// ---------------- digamma (args always >= 1.0 here) ----------------
__device__ __forceinline__ float digammaf_(float x) {
    float r = 0.f;
    while (x < 6.f) { r -= 1.f / x; x += 1.f; }
    float xi = 1.f / x;
    float xi2 = xi * xi;
    return r + logf(x) - 0.5f * xi -
           xi2 * (0.0833333333f - xi2 * (0.0083333333f - xi2 * 0.0039682540f));
}

// ---------------- expectations ----------------
template <int LOGITS>
__global__ void k_expect(const float* __restrict__ Nj, const float* __restrict__ S1,
                         const float* __restrict__ S2, float* __restrict__ m,
                         float* __restrict__ G, float* __restrict__ base,
                         float* __restrict__ logits) {
    int b = blockIdx.x;
    int c = threadIdx.x;
    __shared__ float alph[CC];
    float nj = 0.f;
    if (c < CC) {
        nj = Nj[b * CC + c];
        alph[c] = 1.f + nj;
    }
    __syncthreads();
    if (c < CC) {
        int bc = b * CC + c;
        float asum = 0.f;
#pragma unroll
        for (int k = 0; k < CC; ++k) asum += alph[k];
        float kappa = 1.f + nj;
        float nu = 17.f + nj;
        float S0 = nj - 1e-8f;
        float elnlam = 16.f * 0.69314718056f;
        for (int d = 0; d < 16; ++d) {
            float s1 = S1[bc * 16 + d], s2v = S2[bc * 16 + d];
            float xbar = s1 / nj;
            float sig = (s2v - 2.f * xbar * s1 + xbar * xbar * S0) / nj;
            float Psi = 1.f + nj * sig + (nj / kappa) * xbar * xbar;
            elnlam += digammaf_(0.5f * (nu + 1.f - (float)(d + 1))) - logf(Psi);
            m[bc * 16 + d] = nj * xbar / kappa;
            G[bc * 16 + d] = 0.5f * nu / Psi;
        }
        float elnpi = digammaf_(1.f + nj) - digammaf_(asum);
        float lb = elnpi + 0.5f * elnlam;
        if (LOGITS) logits[bc] = lb;
        base[bc] = lb - 8.f * 1.83787706641f - 8.f / kappa;
    }
}

// ---------------- R update: per (b,n), softmax over c ----------------
__global__ void k_update(const float* __restrict__ pose, const float* __restrict__ Wij,
                         const float* __restrict__ m, const float* __restrict__ G,
                         const float* __restrict__ base, float* __restrict__ R) {
    int b = blockIdx.y;
    int n = blockIdx.x * 256 + threadIdx.x;
    __shared__ float sm[CC][16], sG[CC][16], sb[CC];
    for (int j = threadIdx.x; j < CC * 16; j += 256) {
        sm[j / 16][j % 16] = m[b * CC * 16 + j];
        sG[j / 16][j % 16] = G[b * CC * 16 + j];
    }
    if (threadIdx.x < CC) sb[threadIdx.x] = base[b * CC + threadIdx.x];
    __syncthreads();
    if (n >= NN) return;
    const float4* pp = reinterpret_cast<const float4*>(pose + ((size_t)b * NN + n) * 16);
    alignas(16) float P[16];
    *reinterpret_cast<float4*>(&P[0])  = pp[0];
    *reinterpret_cast<float4*>(&P[4])  = pp[1];
    *reinterpret_cast<float4*>(&P[8])  = pp[2];
    *reinterpret_cast<float4*>(&P[12]) = pp[3];
    int i = n / 36, xy = n % 36;
    float lnp[CC];
    float mx = -1e30f;
#pragma unroll
    for (int c = 0; c < CC; ++c) {
        const float4* wp = reinterpret_cast<const float4*>(Wij + (((size_t)i * CC + c) * 36 + xy) * 16);
        alignas(16) float W[16];
        *reinterpret_cast<float4*>(&W[0])  = wp[0];
        *reinterpret_cast<float4*>(&W[4])  = wp[1];
        *reinterpret_cast<float4*>(&W[8])  = wp[2];
        *reinterpret_cast<float4*>(&W[12]) = wp[3];
        float q = 0.f;
#pragma unroll
        for (int p = 0; p < 4; ++p) {
#pragma unroll
            for (int r = 0; r < 4; ++r) {
                float v = W[p * 4 + 0] * P[0 + r] + W[p * 4 + 1] * P[4 + r] +
                          W[p * 4 + 2] * P[8 + r] + W[p * 4 + 3] * P[12 + r];
                float dm = v - sm[c][p * 4 + r];
                q = fmaf(dm * dm, sG[c][p * 4 + r], q);
            }
        }
        lnp[c] = sb[c] - q;
        mx = fmaxf(mx, lnp[c]);
    }
    float ssum = 0.f;
#pragma unroll
    for (int c = 0; c < CC; ++c) { lnp[c] = expf(lnp[c] - mx); ssum += lnp[c]; }
    float inv = 1.f / ssum;
#pragma unroll
    for (int c = 0; c < CC; ++c) R[((size_t)(b * CC + c)) * NN + n] = lnp[c] * inv;
}

// ---------------- final: BN over batch per class + sigmoid ----------------
__global__ void k_final(const float* __restrict__ logits, float* __restrict__ out) {
    int c = blockIdx.x;
    int b = threadIdx.x;
    float v = logits[b * CC + c];
    float s = v, s2 = v * v;
#pragma unroll
    for (int o = 32; o > 0; o >>= 1) { s += __shfl_down(s, o); s2 += __shfl_down(s2, o); }
    __shared__ float ls[2], lq[2];
    int lane = b & 63, wid = b >> 6;
    if (lane == 0) { ls[wid] = s; lq[wid] = s2; }
    __syncthreads();
    float mu = (ls[0] + ls[1]) * (1.f / 128.f);
    float var = (lq[0] + lq[1]) * (1.f / 128.f) - mu * mu;
    out[b * CC + c] = 1.f / (1.f + expf(-(v - mu) * rsqrtf(var + 1e-5f)));
}

extern "C" void kernel_launch(void* const* d_in, const int* in_sizes, int n_in,
                              void* d_out, int out_size, void* d_ws, size_t ws_size,
                              hipStream_t stream) {
    (void)in_sizes; (void)n_in; (void)out_size; (void)ws_size;
    const float* x       = (const float*)d_in[0];
    const float* conv1_w = (const float*)d_in[1];
    const float* bn1_g   = (const float*)d_in[2];
    const float* bn1_b   = (const float*)d_in[3];
    const float* prim_w  = (const float*)d_in[4];
    const float* bna_g   = (const float*)d_in[5];
    const float* bna_b   = (const float*)d_in[6];
    const float* bnp_g   = (const float*)d_in[7];
    const float* bnp_b   = (const float*)d_in[8];
    const float* Wij     = (const float*)d_in[9];

    float* ws = (float*)d_ws;
    float* h    = ws;                                         // 3,211,264 f32
    float* pcT  = ws + 3211264;                               // 2,506,752 f32 [4608][544]
    float* pose = ws + 5718016;                               // 2,359,296 f32
    float* ai   = ws + 8077312;                               //   147,456 f32
    float* R    = ws + 8224768;                               // 1,474,560 f32
    unsigned short* Ahp = (unsigned short*)(ws + 9699328);    //   663,552 bf16
    unsigned short* Alp = (unsigned short*)(ws + 10031104);   //   663,552 bf16
    float* bn1    = ws + 10362880;   // 256
    float* bn2    = ws + 10363136;   // 128
    float* Nj     = ws + 10363264;   // 1,280
    float* S1     = ws + 10364544;   // 20,480
    float* S2     = ws + 10385024;   // 20,480
    float* m      = ws + 10405504;   // 20,480
    float* G      = ws + 10425984;   // 20,480
    float* base   = ws + 10446464;   // 1,280
    float* logits = ws + 10447744;   // 1,280
    float* out    = (float*)d_out;

    k_conv1<<<dim3(7, 128), 256, 0, stream>>>(x, conv1_w, h);
    k_bnstats1<<<128, 256, 0, stream>>>(h, bn1_g, bn1_b, bn1);
    k_prepw<<<324, 256, 0, stream>>>(prim_w, Ahp, Alp);
    k_gemm<<<dim3(3, 72), 256, 0, stream>>>(Ahp, Alp, h, bn1, pcT);
    k_bnstats2<<<64, 256, 0, stream>>>(pcT, bna_g, bna_b, bnp_g, bnp_b, bn2);
    k_transform<<<576, 256, 0, stream>>>(pcT, bn2, pose, ai);

    // routing iter 0 (R implicit = 1/C)
    k_stats<1><<<320, 256, 0, stream>>>(pose, ai, R, Wij, Nj, S1, S2);
    k_expect<0><<<128, 64, 0, stream>>>(Nj, S1, S2, m, G, base, logits);
    k_update<<<dim3(5, 128), 256, 0, stream>>>(pose, Wij, m, G, base, R);
    // iter 1
    k_stats<0><<<320, 256, 0, stream>>>(pose, ai, R, Wij, Nj, S1, S2);
    k_expect<0><<<128, 64, 0, stream>>>(Nj, S1, S2, m, G, base, logits);
    k_update<<<dim3(5, 128), 256, 0, stream>>>(pose, Wij, m, G, base, R);
    // iter 2 (stats + expectations only)
    k_stats<0><<<320, 256, 0, stream>>>(pose, ai, R, Wij, Nj, S1, S2);
    k_expect<1><<<128, 64, 0, stream>>>(Nj, S1, S2, m, G, base, logits);

    k_final<<<10, 128, 0, stream>>>(logits, out);
}

// Round 10
// 285.336 us; speedup vs baseline: 1.0977x; 1.0977x over previous
//
#include <hip/hip_runtime.h>
#include <hip/hip_bf16.h>

// Problem constants
#define NB 128     // batch
#define AA 128     // conv1 out channels
#define BB 32      // capsule types
#define CC 10      // classes
#define KK 6       // primary grid
#define DD 16      // pose dim
#define NN 1152    // B*K*K
#define H1 14      // conv1 out spatial
#define CH2 544    // B*D+B
#define NG 4608    // GEMM N = NB*36
#define KG 1152    // GEMM K = 128*9
#define MG 576     // GEMM M padded (544 -> 9*64)

typedef short bfrag8 __attribute__((ext_vector_type(8)));   // 8 bf16 (4 VGPRs)
typedef float facc4 __attribute__((ext_vector_type(4)));    // 4 fp32 acc

__device__ __forceinline__ unsigned short f2bf(float f) {   // RNE f32->bf16
    unsigned u = __float_as_uint(f);
    u += 0x7FFF + ((u >> 16) & 1);
    return (unsigned short)(u >> 16);
}
__device__ __forceinline__ float bf2f(unsigned short s) {
    return __uint_as_float(((unsigned)s) << 16);
}

// ---------------- conv1 (LDS-staged): (128,3,32,32) -> (128,128,14,14), 5x5 s2 --------
__global__ __launch_bounds__(256, 3) void k_conv1(const float* __restrict__ x,
                                                  const float* __restrict__ w,
                                                  float* __restrict__ h) {
    __shared__ __align__(16) float sX[3][7][32];   //  2,688 B
    __shared__ float sWf[AA * 75];                 // 38,400 B
    const int p = blockIdx.x;
    const int b = blockIdx.y;
    const int tid = threadIdx.x;
    for (int j = tid; j < AA * 75; j += 256) sWf[j] = w[j];
    for (int j = tid; j < 3 * 7 * 32; j += 256) {
        int col = j & 31; int t2 = j >> 5; int row = t2 % 7; int ic = t2 / 7;
        sX[ic][row][col] = x[b * 3072 + ic * 1024 + (4 * p + row) * 32 + col];
    }
    __syncthreads();
    const int oc = tid & 127, ry = tid >> 7;
    const int r = 2 * p + ry;
    float acc[14];
#pragma unroll
    for (int j = 0; j < 14; ++j) acc[j] = 0.f;
    const float* wr = sWf + oc * 75;
#pragma unroll
    for (int ic = 0; ic < 3; ++ic) {
#pragma unroll
        for (int ky = 0; ky < 5; ++ky) {
            const float* xr = &sX[ic][2 * ry + ky][0];
            float row[32];
#pragma unroll
            for (int q = 0; q < 8; ++q) {
                float4 v = *reinterpret_cast<const float4*>(xr + q * 4);
                row[q * 4 + 0] = v.x; row[q * 4 + 1] = v.y;
                row[q * 4 + 2] = v.z; row[q * 4 + 3] = v.w;
            }
            float w0 = wr[ic * 25 + ky * 5 + 0];
            float w1 = wr[ic * 25 + ky * 5 + 1];
            float w2 = wr[ic * 25 + ky * 5 + 2];
            float w3 = wr[ic * 25 + ky * 5 + 3];
            float w4 = wr[ic * 25 + ky * 5 + 4];
#pragma unroll
            for (int ox = 0; ox < 14; ++ox) {
                float s = acc[ox];
                s = fmaf(row[2 * ox + 0], w0, s);
                s = fmaf(row[2 * ox + 1], w1, s);
                s = fmaf(row[2 * ox + 2], w2, s);
                s = fmaf(row[2 * ox + 3], w3, s);
                s = fmaf(row[2 * ox + 4], w4, s);
                acc[ox] = s;
            }
        }
    }
    float* out = h + ((size_t)(b * AA + oc) * 14 + r) * 14;
#pragma unroll
    for (int q = 0; q < 7; ++q)
        *reinterpret_cast<float2*>(out + q * 2) = make_float2(acc[q * 2], acc[q * 2 + 1]);
}

// ---------------- bn1 stats: per-channel mean/var over (b, 14, 14) ----------------
__global__ void k_bnstats1(const float* __restrict__ h, const float* __restrict__ g,
                           const float* __restrict__ be, float* __restrict__ bn1) {
    int c = blockIdx.x;
    int tid = threadIdx.x;
    float s = 0.f, s2 = 0.f;
    for (int j = tid; j < NB * 196; j += 256) {
        int b = j / 196, hw = j % 196;
        float v = h[(b * AA + c) * 196 + hw];
        s += v; s2 += v * v;
    }
#pragma unroll
    for (int o = 32; o > 0; o >>= 1) { s += __shfl_down(s, o); s2 += __shfl_down(s2, o); }
    __shared__ float ls[4], lq[4];
    int lane = tid & 63, wid = tid >> 6;
    if (lane == 0) { ls[wid] = s; lq[wid] = s2; }
    __syncthreads();
    if (tid == 0) {
        s = ls[0] + ls[1] + ls[2] + ls[3];
        s2 = lq[0] + lq[1] + lq[2] + lq[3];
        const float n = (float)(NB * 196);
        float mu = s / n;
        float var = s2 / n - mu * mu;
        float sc = g[c] * rsqrtf(var + 1e-5f);
        bn1[c] = sc;
        bn1[AA + c] = be[c] - mu * sc;
    }
}

// ---------------- prep weights: prim_w [544][1152] f32 -> Ah/Al [576][1152] bf16 ------
__global__ void k_prepw(const float* __restrict__ w, unsigned short* __restrict__ Ah,
                        unsigned short* __restrict__ Al) {
    int t = blockIdx.x * 256 + threadIdx.x;
    if (t >= MG * (KG / 8)) return;
    int row = t / (KG / 8), seg = t % (KG / 8);
    alignas(16) unsigned short hi[8], lo[8];
    if (row < CH2) {
        const float* src = w + (size_t)row * KG + seg * 8;
#pragma unroll
        for (int j = 0; j < 8; ++j) {
            float v = src[j];
            unsigned short hh = f2bf(v);
            hi[j] = hh;
            lo[j] = f2bf(v - bf2f(hh));
        }
    } else {
#pragma unroll
        for (int j = 0; j < 8; ++j) { hi[j] = 0; lo[j] = 0; }
    }
    *reinterpret_cast<uint4*>(Ah + (size_t)row * KG + seg * 8) = *reinterpret_cast<const uint4*>(hi);
    *reinterpret_cast<uint4*>(Al + (size_t)row * KG + seg * 8) = *reinterpret_cast<const uint4*>(lo);
}

// ---------------- conv2: fused im2col + split-bf16 MFMA GEMM, 64x64 tiles ----------
// pcT[n][oc] = sum_k A[oc][k] * B[n][k],  B built on the fly from h (+bn1+relu).
// grid (9, 72): 648 blocks (2.5/CU). 256 threads = 4 waves (2M x 2N), 12 MFMA/step.
// Pipelined: global loads for step ks+1 issue before COMPUTE(ks).
__global__ __launch_bounds__(256) void k_gemm(const unsigned short* __restrict__ Ah,
                                              const unsigned short* __restrict__ Al,
                                              const float* __restrict__ h,
                                              const float* __restrict__ bn1,
                                              float* __restrict__ pcT) {
    __shared__ alignas(16) unsigned short sAh[64][44], sAl[64][44];   // 11,264 B
    __shared__ alignas(16) unsigned short sBh[64][44], sBl[64][44];   // 11,264 B
    __shared__ float sBn[2 * AA];                                     //  1,024 B
    const int m0 = blockIdx.x * 64;
    const int n0 = blockIdx.y * 64;
    const int tid = threadIdx.x;
    const int lane = tid & 63, wv = tid >> 6;
    const int wm = wv >> 1, wn = wv & 1;
    const int quad = lane >> 4, r16 = lane & 15;

    // staging slots: row/nn = tid>>2, k-octet = tid&3 (1 uint4 per plane per thread)
    const int arow = tid >> 2, aseg = tid & 3;
    const int nn = arow, koct = aseg;
    const int nglob = n0 + nn;
    const int bb = nglob / 36, xy = nglob % 36;
    const int oy = xy / 6, ox = xy % 6;
    const float* hbase = h + (size_t)bb * (AA * 196) + (2 * oy) * 14 + 2 * ox;

    sBn[tid] = bn1[tid];   // 256 == 2*AA

    uint4 vAh, vAl;
    float raw[8];

    // LOAD(0)
    {
        size_t off = (size_t)(m0 + arow) * KG + aseg * 8;
        vAh = *reinterpret_cast<const uint4*>(Ah + off);
        vAl = *reinterpret_cast<const uint4*>(Al + off);
#pragma unroll
        for (int j = 0; j < 8; ++j) {
            int k = koct * 8 + j;
            int ic = k / 9, r9 = k - ic * 9;
            int ky = r9 / 3, kx = r9 - ky * 3;
            raw[j] = hbase[ic * 196 + ky * 14 + kx];
        }
    }

    facc4 acc[2][2] = {};

#pragma unroll 1
    for (int ks = 0; ks < KG / 32; ++ks) {
        __syncthreads();   // previous compute done reading LDS (and sBn ready on iter 0)
        // WRITE(ks): regs -> LDS
        *reinterpret_cast<uint4*>(&sAh[arow][aseg * 8]) = vAh;
        *reinterpret_cast<uint4*>(&sAl[arow][aseg * 8]) = vAl;
        {
            alignas(16) unsigned short hi8[8], lo8[8];
            const int kb = ks * 32 + koct * 8;
#pragma unroll
            for (int j = 0; j < 8; ++j) {
                int ic = (kb + j) / 9;
                float v = fmaf(raw[j], sBn[ic], sBn[AA + ic]);
                v = fmaxf(v, 0.f);
                unsigned short hh = f2bf(v);
                hi8[j] = hh;
                lo8[j] = f2bf(v - bf2f(hh));
            }
            *reinterpret_cast<uint4*>(&sBh[nn][koct * 8]) = *reinterpret_cast<const uint4*>(hi8);
            *reinterpret_cast<uint4*>(&sBl[nn][koct * 8]) = *reinterpret_cast<const uint4*>(lo8);
        }
        __syncthreads();
        // LOAD(ks+1): issue early, lands during compute
        if (ks + 1 < KG / 32) {
            const int k0n = (ks + 1) * 32;
            size_t off = (size_t)(m0 + arow) * KG + k0n + aseg * 8;
            vAh = *reinterpret_cast<const uint4*>(Ah + off);
            vAl = *reinterpret_cast<const uint4*>(Al + off);
#pragma unroll
            for (int j = 0; j < 8; ++j) {
                int k = k0n + koct * 8 + j;
                int ic = k / 9, r9 = k - ic * 9;
                int ky = r9 / 3, kx = r9 - ky * 3;
                raw[j] = hbase[ic * 196 + ky * 14 + kx];
            }
        }
        // COMPUTE(ks)
        bfrag8 ah[2], al[2], bhf[2], blf[2];
#pragma unroll
        for (int i = 0; i < 2; ++i) {
            ah[i]  = *reinterpret_cast<const bfrag8*>(&sAh[wm * 32 + i * 16 + r16][quad * 8]);
            al[i]  = *reinterpret_cast<const bfrag8*>(&sAl[wm * 32 + i * 16 + r16][quad * 8]);
            bhf[i] = *reinterpret_cast<const bfrag8*>(&sBh[wn * 32 + i * 16 + r16][quad * 8]);
            blf[i] = *reinterpret_cast<const bfrag8*>(&sBl[wn * 32 + i * 16 + r16][quad * 8]);
        }
#pragma unroll
        for (int i = 0; i < 2; ++i)
#pragma unroll
            for (int j = 0; j < 2; ++j) {
                acc[i][j] = __builtin_amdgcn_mfma_f32_16x16x32_bf16(ah[i], bhf[j], acc[i][j], 0, 0, 0);
                acc[i][j] = __builtin_amdgcn_mfma_f32_16x16x32_bf16(ah[i], blf[j], acc[i][j], 0, 0, 0);
                acc[i][j] = __builtin_amdgcn_mfma_f32_16x16x32_bf16(al[i], bhf[j], acc[i][j], 0, 0, 0);
            }
    }
    // D mapping: col = lane&15 -> n, row = quad*4+reg -> oc (contiguous float4 in oc)
#pragma unroll
    for (int i = 0; i < 2; ++i) {
        int oc_base = m0 + wm * 32 + i * 16 + quad * 4;
        if (oc_base >= CH2) continue;
#pragma unroll
        for (int j = 0; j < 2; ++j) {
            int n = n0 + wn * 32 + j * 16 + r16;
            *reinterpret_cast<facc4*>(pcT + (size_t)n * CH2 + oc_base) = acc[i][j];
        }
    }
}

// ---------------- bn stats on pcT[n][oc] ----------------
__global__ void k_bnstats2(const float* __restrict__ pcT,
                           const float* __restrict__ bna_g, const float* __restrict__ bna_b,
                           const float* __restrict__ bnp_g, const float* __restrict__ bnp_b,
                           float* __restrict__ bn2) {
    int blk = blockIdx.x;
    int tid = threadIdx.x;
    float s = 0.f, s2 = 0.f;
    if (blk < 32) {
        int i = blk;
        for (int j = tid; j < NG * 4; j += 256) {
            int row = j >> 2, q = j & 3;
            float4 v = *reinterpret_cast<const float4*>(pcT + (size_t)row * CH2 + i * 16 + q * 4);
            s += v.x + v.y + v.z + v.w;
            s2 += v.x * v.x + v.y * v.y + v.z * v.z + v.w * v.w;
        }
    } else {
        int i = blk - 32;
        for (int j = tid; j < NG; j += 256) {
            float v = pcT[(size_t)j * CH2 + BB * DD + i];
            s += v; s2 += v * v;
        }
    }
#pragma unroll
    for (int o = 32; o > 0; o >>= 1) { s += __shfl_down(s, o); s2 += __shfl_down(s2, o); }
    __shared__ float ls[4], lq[4];
    int lane = tid & 63, wid = tid >> 6;
    if (lane == 0) { ls[wid] = s; lq[wid] = s2; }
    __syncthreads();
    if (tid == 0) {
        s = ls[0] + ls[1] + ls[2] + ls[3];
        s2 = lq[0] + lq[1] + lq[2] + lq[3];
        if (blk < 32) {
            int i = blk;
            const float n = (float)(NB * DD * 36);
            float mu = s / n, var = s2 / n - mu * mu;
            float sc = bnp_g[i] * rsqrtf(var + 1e-5f);
            bn2[i] = sc; bn2[32 + i] = bnp_b[i] - mu * sc;
        } else {
            int i = blk - 32;
            const float n = (float)(NB * 36);
            float mu = s / n, var = s2 / n - mu * mu;
            float sc = bna_g[i] * rsqrtf(var + 1e-5f);
            bn2[64 + i] = sc; bn2[96 + i] = bna_b[i] - mu * sc;
        }
    }
}

// ---------------- transform: pcT -> poses_bn (b,n,16) and a_i (b,n) ----------------
__global__ void k_transform(const float* __restrict__ pcT, const float* __restrict__ bn2,
                            float* __restrict__ pose, float* __restrict__ ai) {
    int idx = blockIdx.x * 256 + threadIdx.x;
    if (idx >= NB * NN) return;
    int b = idx / NN, n = idx % NN;
    int i = n / 36, xy = n % 36;
    int row = b * 36 + xy;
    float sc = bn2[i], sh = bn2[32 + i];
    const float* src = pcT + (size_t)row * CH2 + i * 16;
    float* pd = pose + (size_t)idx * 16;
#pragma unroll
    for (int q = 0; q < 4; ++q) {
        float4 v = *reinterpret_cast<const float4*>(src + q * 4);
        v.x = fmaf(v.x, sc, sh); v.y = fmaf(v.y, sc, sh);
        v.z = fmaf(v.z, sc, sh); v.w = fmaf(v.w, sc, sh);
        *reinterpret_cast<float4*>(pd + q * 4) = v;
    }
    float va = fmaf(pcT[(size_t)row * CH2 + BB * DD + i], bn2[64 + i], bn2[96 + i]);
    ai[idx] = 1.f / (1.f + expf(-va));
}

// ---------------- VB stats: one wave per (b,c) ----------------
template <int FIRST>
__global__ void k_stats(const float* __restrict__ pose, const float* __restrict__ ai,
                        const float* __restrict__ R, const float* __restrict__ Wij,
                        float* __restrict__ Nj, float* __restrict__ S1, float* __restrict__ S2) {
    int bc = blockIdx.x * 4 + (threadIdx.x >> 6);
    int lane = threadIdx.x & 63;
    int c = bc % CC, b = bc / CC;
    float s0 = 0.f;
    float s1[16], s2[16];
#pragma unroll
    for (int k = 0; k < 16; ++k) { s1[k] = 0.f; s2[k] = 0.f; }
    for (int n = lane; n < NN; n += 64) {
        int i = n / 36, xy = n % 36;
        const float4* pp = reinterpret_cast<const float4*>(pose + ((size_t)b * NN + n) * 16);
        const float4* wp = reinterpret_cast<const float4*>(Wij + (((size_t)i * CC + c) * 36 + xy) * 16);
        alignas(16) float P[16], W[16];
        *reinterpret_cast<float4*>(&P[0])  = pp[0];
        *reinterpret_cast<float4*>(&P[4])  = pp[1];
        *reinterpret_cast<float4*>(&P[8])  = pp[2];
        *reinterpret_cast<float4*>(&P[12]) = pp[3];
        *reinterpret_cast<float4*>(&W[0])  = wp[0];
        *reinterpret_cast<float4*>(&W[4])  = wp[1];
        *reinterpret_cast<float4*>(&W[8])  = wp[2];
        *reinterpret_cast<float4*>(&W[12]) = wp[3];
        float wgt = ai[b * NN + n];
        if (FIRST) wgt *= 0.1f;
        else wgt *= R[((size_t)(b * CC + c)) * NN + n];
        s0 += wgt;
#pragma unroll
        for (int p = 0; p < 4; ++p) {
#pragma unroll
            for (int r = 0; r < 4; ++r) {
                float v = W[p * 4 + 0] * P[0 + r] + W[p * 4 + 1] * P[4 + r] +
                          W[p * 4 + 2] * P[8 + r] + W[p * 4 + 3] * P[12 + r];
                int d = p * 4 + r;
                float wv = wgt * v;
                s1[d] += wv;
                s2[d] = fmaf(wv, v, s2[d]);
            }
        }
    }
#pragma unroll
    for (int o = 32; o > 0; o >>= 1) {
        s0 += __shfl_down(s0, o);
#pragma unroll
        for (int k = 0; k < 16; ++k) {
            s1[k] += __shfl_down(s1[k], o);
            s2[k] += __shfl_down(s2[k], o);
        }
    }
    if (lane == 0) {
        Nj[bc] = s0 + 1e-8f;
#pragma unroll
        for (int k = 0; k < 16; ++k) { S1[bc * 16 + k] = s1[k]; S2[bc * 16 + k] = s2[k]; }
    }
}

// ---------------- digamma (args always >= 1.0 here) ----------------
__device__ __forceinline__ float digammaf_(float x) {
    float r = 0.f;
    while (x < 6.f) { r -= 1.f / x; x += 1.f; }
    float xi = 1.f / x;
    float xi2 = xi * xi;
    return r + logf(x) - 0.5f * xi -
           xi2 * (0.0833333333f - xi2 * (0.0083333333f - xi2 * 0.0039682540f));
}

// ---------------- expectations ----------------
template <int LOGITS>
__global__ void k_expect(const float* __restrict__ Nj, const float* __restrict__ S1,
                         const float* __restrict__ S2, float* __restrict__ m,
                         float* __restrict__ G, float* __restrict__ base,
                         float* __restrict__ logits) {
    int b = blockIdx.x;
    int c = threadIdx.x;
    __shared__ float alph[CC];
    float nj = 0.f;
    if (c < CC) {
        nj = Nj[b * CC + c];
        alph[c] = 1.f + nj;
    }
    __syncthreads();
    if (c < CC) {
        int bc = b * CC + c;
        float asum = 0.f;
#pragma unroll
        for (int k = 0; k < CC; ++k) asum += alph[k];
        float kappa = 1.f + nj;
        float nu = 17.f + nj;
        float S0 = nj - 1e-8f;
        float elnlam = 16.f * 0.69314718056f;
        for (int d = 0; d < 16; ++d) {
            float s1 = S1[bc * 16 + d], s2v = S2[bc * 16 + d];
            float xbar = s1 / nj;
            float sig = (s2v - 2.f * xbar * s1 + xbar * xbar * S0) / nj;
            float Psi = 1.f + nj * sig + (nj / kappa) * xbar * xbar;
            elnlam += digammaf_(0.5f * (nu + 1.f - (float)(d + 1))) - logf(Psi);
            m[bc * 16 + d] = nj * xbar / kappa;
            G[bc * 16 + d] = 0.5f * nu / Psi;
        }
        float elnpi = digammaf_(1.f + nj) - digammaf_(asum);
        float lb = elnpi + 0.5f * elnlam;
        if (LOGITS) logits[bc] = lb;
        base[bc] = lb - 8.f * 1.83787706641f - 8.f / kappa;
    }
}

// ---------------- R update: per (b,n), softmax over c ----------------
__global__ void k_update(const float* __restrict__ pose, const float* __restrict__ Wij,
                         const float* __restrict__ m, const float* __restrict__ G,
                         const float* __restrict__ base, float* __restrict__ R) {
    int b = blockIdx.y;
    int n = blockIdx.x * 256 + threadIdx.x;
    __shared__ float sm[CC][16], sG[CC][16], sb[CC];
    for (int j = threadIdx.x; j < CC * 16; j += 256) {
        sm[j / 16][j % 16] = m[b * CC * 16 + j];
        sG[j / 16][j % 16] = G[b * CC * 16 + j];
    }
    if (threadIdx.x < CC) sb[threadIdx.x] = base[b * CC + threadIdx.x];
    __syncthreads();
    if (n >= NN) return;
    const float4* pp = reinterpret_cast<const float4*>(pose + ((size_t)b * NN + n) * 16);
    alignas(16) float P[16];
    *reinterpret_cast<float4*>(&P[0])  = pp[0];
    *reinterpret_cast<float4*>(&P[4])  = pp[1];
    *reinterpret_cast<float4*>(&P[8])  = pp[2];
    *reinterpret_cast<float4*>(&P[12]) = pp[3];
    int i = n / 36, xy = n % 36;
    float lnp[CC];
    float mx = -1e30f;
#pragma unroll
    for (int c = 0; c < CC; ++c) {
        const float4* wp = reinterpret_cast<const float4*>(Wij + (((size_t)i * CC + c) * 36 + xy) * 16);
        alignas(16) float W[16];
        *reinterpret_cast<float4*>(&W[0])  = wp[0];
        *reinterpret_cast<float4*>(&W[4])  = wp[1];
        *reinterpret_cast<float4*>(&W[8])  = wp[2];
        *reinterpret_cast<float4*>(&W[12]) = wp[3];
        float q = 0.f;
#pragma unroll
        for (int p = 0; p < 4; ++p) {
#pragma unroll
            for (int r = 0; r < 4; ++r) {
                float v = W[p * 4 + 0] * P[0 + r] + W[p * 4 + 1] * P[4 + r] +
                          W[p * 4 + 2] * P[8 + r] + W[p * 4 + 3] * P[12 + r];
                float dm = v - sm[c][p * 4 + r];
                q = fmaf(dm * dm, sG[c][p * 4 + r], q);
            }
        }
        lnp[c] = sb[c] - q;
        mx = fmaxf(mx, lnp[c]);
    }
    float ssum = 0.f;
#pragma unroll
    for (int c = 0; c < CC; ++c) { lnp[c] = expf(lnp[c] - mx); ssum += lnp[c]; }
    float inv = 1.f / ssum;
#pragma unroll
    for (int c = 0; c < CC; ++c) R[((size_t)(b * CC + c)) * NN + n] = lnp[c] * inv;
}

// ---------------- final: BN over batch per class + sigmoid ----------------
__global__ void k_final(const float* __restrict__ logits, float* __restrict__ out) {
    int c = blockIdx.x;
    int b = threadIdx.x;
    float v = logits[b * CC + c];
    float s = v, s2 = v * v;
#pragma unroll
    for (int o = 32; o > 0; o >>= 1) { s += __shfl_down(s, o); s2 += __shfl_down(s2, o); }
    __shared__ float ls[2], lq[2];
    int lane = b & 63, wid = b >> 6;
    if (lane == 0) { ls[wid] = s; lq[wid] = s2; }
    __syncthreads();
    float mu = (ls[0] + ls[1]) * (1.f / 128.f);
    float var = (lq[0] + lq[1]) * (1.f / 128.f) - mu * mu;
    out[b * CC + c] = 1.f / (1.f + expf(-(v - mu) * rsqrtf(var + 1e-5f)));
}

extern "C" void kernel_launch(void* const* d_in, const int* in_sizes, int n_in,
                              void* d_out, int out_size, void* d_ws, size_t ws_size,
                              hipStream_t stream) {
    (void)in_sizes; (void)n_in; (void)out_size; (void)ws_size;
    const float* x       = (const float*)d_in[0];
    const float* conv1_w = (const float*)d_in[1];
    const float* bn1_g   = (const float*)d_in[2];
    const float* bn1_b   = (const float*)d_in[3];
    const float* prim_w  = (const float*)d_in[4];
    const float* bna_g   = (const float*)d_in[5];
    const float* bna_b   = (const float*)d_in[6];
    const float* bnp_g   = (const float*)d_in[7];
    const float* bnp_b   = (const float*)d_in[8];
    const float* Wij     = (const float*)d_in[9];

    float* ws = (float*)d_ws;
    float* h    = ws;                                         // 3,211,264 f32
    float* pcT  = ws + 3211264;                               // 2,506,752 f32 [4608][544]
    float* pose = ws + 5718016;                               // 2,359,296 f32
    float* ai   = ws + 8077312;                               //   147,456 f32
    float* R    = ws + 8224768;                               // 1,474,560 f32
    unsigned short* Ahp = (unsigned short*)(ws + 9699328);    //   663,552 bf16
    unsigned short* Alp = (unsigned short*)(ws + 10031104);   //   663,552 bf16
    float* bn1    = ws + 10362880;   // 256
    float* bn2    = ws + 10363136;   // 128
    float* Nj     = ws + 10363264;   // 1,280
    float* S1     = ws + 10364544;   // 20,480
    float* S2     = ws + 10385024;   // 20,480
    float* m      = ws + 10405504;   // 20,480
    float* G      = ws + 10425984;   // 20,480
    float* base   = ws + 10446464;   // 1,280
    float* logits = ws + 10447744;   // 1,280
    float* out    = (float*)d_out;

    k_conv1<<<dim3(7, 128), 256, 0, stream>>>(x, conv1_w, h);
    k_bnstats1<<<128, 256, 0, stream>>>(h, bn1_g, bn1_b, bn1);
    k_prepw<<<324, 256, 0, stream>>>(prim_w, Ahp, Alp);
    k_gemm<<<dim3(9, 72), 256, 0, stream>>>(Ahp, Alp, h, bn1, pcT);
    k_bnstats2<<<64, 256, 0, stream>>>(pcT, bna_g, bna_b, bnp_g, bnp_b, bn2);
    k_transform<<<576, 256, 0, stream>>>(pcT, bn2, pose, ai);

    // routing iter 0 (R implicit = 1/C)
    k_stats<1><<<320, 256, 0, stream>>>(pose, ai, R, Wij, Nj, S1, S2);
    k_expect<0><<<128, 64, 0, stream>>>(Nj, S1, S2, m, G, base, logits);
    k_update<<<dim3(5, 128), 256, 0, stream>>>(pose, Wij, m, G, base, R);
    // iter 1
    k_stats<0><<<320, 256, 0, stream>>>(pose, ai, R, Wij, Nj, S1, S2);
    k_expect<0><<<128, 64, 0, stream>>>(Nj, S1, S2, m, G, base, logits);
    k_update<<<dim3(5, 128), 256, 0, stream>>>(pose, Wij, m, G, base, R);
    // iter 2 (stats + expectations only)
    k_stats<0><<<320, 256, 0, stream>>>(pose, ai, R, Wij, Nj, S1, S2);
    k_expect<1><<<128, 64, 0, stream>>>(Nj, S1, S2, m, G, base, logits);

    k_final<<<10, 128, 0, stream>>>(logits, out);
}

// Round 11
// 248.456 us; speedup vs baseline: 1.2606x; 1.1484x over previous
//
#include <hip/hip_runtime.h>
#include <hip/hip_bf16.h>

// Problem constants
#define NB 128     // batch
#define AA 128     // conv1 out channels
#define BB 32      // capsule types
#define CC 10      // classes
#define KK 6       // primary grid
#define DD 16      // pose dim
#define NN 1152    // B*K*K
#define H1 14      // conv1 out spatial
#define CH2 544    // B*D+B
#define NG 4608    // GEMM N = NB*36
#define KG 1152    // GEMM K = 128*9
#define MG 576     // GEMM M padded (544 -> 9*64)

typedef short bfrag8 __attribute__((ext_vector_type(8)));   // 8 bf16 (4 VGPRs)
typedef float facc4 __attribute__((ext_vector_type(4)));    // 4 fp32 acc

__device__ __forceinline__ unsigned short f2bf(float f) {   // RNE f32->bf16
    unsigned u = __float_as_uint(f);
    u += 0x7FFF + ((u >> 16) & 1);
    return (unsigned short)(u >> 16);
}
__device__ __forceinline__ float bf2f(unsigned short s) {
    return __uint_as_float(((unsigned)s) << 16);
}

// ---------------- conv1 (LDS-staged): (128,3,32,32) -> (128,128,14,14), 5x5 s2 --------
__global__ __launch_bounds__(256, 3) void k_conv1(const float* __restrict__ x,
                                                  const float* __restrict__ w,
                                                  float* __restrict__ h) {
    __shared__ __align__(16) float sX[3][7][32];   //  2,688 B
    __shared__ float sWf[AA * 75];                 // 38,400 B
    const int p = blockIdx.x;
    const int b = blockIdx.y;
    const int tid = threadIdx.x;
    for (int j = tid; j < AA * 75; j += 256) sWf[j] = w[j];
    for (int j = tid; j < 3 * 7 * 32; j += 256) {
        int col = j & 31; int t2 = j >> 5; int row = t2 % 7; int ic = t2 / 7;
        sX[ic][row][col] = x[b * 3072 + ic * 1024 + (4 * p + row) * 32 + col];
    }
    __syncthreads();
    const int oc = tid & 127, ry = tid >> 7;
    const int r = 2 * p + ry;
    float acc[14];
#pragma unroll
    for (int j = 0; j < 14; ++j) acc[j] = 0.f;
    const float* wr = sWf + oc * 75;
#pragma unroll
    for (int ic = 0; ic < 3; ++ic) {
#pragma unroll
        for (int ky = 0; ky < 5; ++ky) {
            const float* xr = &sX[ic][2 * ry + ky][0];
            float row[32];
#pragma unroll
            for (int q = 0; q < 8; ++q) {
                float4 v = *reinterpret_cast<const float4*>(xr + q * 4);
                row[q * 4 + 0] = v.x; row[q * 4 + 1] = v.y;
                row[q * 4 + 2] = v.z; row[q * 4 + 3] = v.w;
            }
            float w0 = wr[ic * 25 + ky * 5 + 0];
            float w1 = wr[ic * 25 + ky * 5 + 1];
            float w2 = wr[ic * 25 + ky * 5 + 2];
            float w3 = wr[ic * 25 + ky * 5 + 3];
            float w4 = wr[ic * 25 + ky * 5 + 4];
#pragma unroll
            for (int ox = 0; ox < 14; ++ox) {
                float s = acc[ox];
                s = fmaf(row[2 * ox + 0], w0, s);
                s = fmaf(row[2 * ox + 1], w1, s);
                s = fmaf(row[2 * ox + 2], w2, s);
                s = fmaf(row[2 * ox + 3], w3, s);
                s = fmaf(row[2 * ox + 4], w4, s);
                acc[ox] = s;
            }
        }
    }
    float* out = h + ((size_t)(b * AA + oc) * 14 + r) * 14;
#pragma unroll
    for (int q = 0; q < 7; ++q)
        *reinterpret_cast<float2*>(out + q * 2) = make_float2(acc[q * 2], acc[q * 2 + 1]);
}

// ---------------- bn1 stats: per-channel mean/var over (b, 14, 14) ----------------
__global__ void k_bnstats1(const float* __restrict__ h, const float* __restrict__ g,
                           const float* __restrict__ be, float* __restrict__ bn1) {
    int c = blockIdx.x;
    int tid = threadIdx.x;
    float s = 0.f, s2 = 0.f;
    for (int j = tid; j < NB * 196; j += 256) {
        int b = j / 196, hw = j % 196;
        float v = h[(b * AA + c) * 196 + hw];
        s += v; s2 += v * v;
    }
#pragma unroll
    for (int o = 32; o > 0; o >>= 1) { s += __shfl_down(s, o); s2 += __shfl_down(s2, o); }
    __shared__ float ls[4], lq[4];
    int lane = tid & 63, wid = tid >> 6;
    if (lane == 0) { ls[wid] = s; lq[wid] = s2; }
    __syncthreads();
    if (tid == 0) {
        s = ls[0] + ls[1] + ls[2] + ls[3];
        s2 = lq[0] + lq[1] + lq[2] + lq[3];
        const float n = (float)(NB * 196);
        float mu = s / n;
        float var = s2 / n - mu * mu;
        float sc = g[c] * rsqrtf(var + 1e-5f);
        bn1[c] = sc;
        bn1[AA + c] = be[c] - mu * sc;
    }
}

// ---------------- prep weights: prim_w [544][1152] f32 -> Ah/Al [576][1152] bf16 ------
__global__ void k_prepw(const float* __restrict__ w, unsigned short* __restrict__ Ah,
                        unsigned short* __restrict__ Al) {
    int t = blockIdx.x * 256 + threadIdx.x;
    if (t >= MG * (KG / 8)) return;
    int row = t / (KG / 8), seg = t % (KG / 8);
    alignas(16) unsigned short hi[8], lo[8];
    if (row < CH2) {
        const float* src = w + (size_t)row * KG + seg * 8;
#pragma unroll
        for (int j = 0; j < 8; ++j) {
            float v = src[j];
            unsigned short hh = f2bf(v);
            hi[j] = hh;
            lo[j] = f2bf(v - bf2f(hh));
        }
    } else {
#pragma unroll
        for (int j = 0; j < 8; ++j) { hi[j] = 0; lo[j] = 0; }
    }
    *reinterpret_cast<uint4*>(Ah + (size_t)row * KG + seg * 8) = *reinterpret_cast<const uint4*>(hi);
    *reinterpret_cast<uint4*>(Al + (size_t)row * KG + seg * 8) = *reinterpret_cast<const uint4*>(lo);
}

// ---------------- im2col + fused bn1+relu: h -> Bh/Bl [4608][1152] bf16 ---------------
__global__ void k_im2col(const float* __restrict__ h, const float* __restrict__ bn1,
                         unsigned short* __restrict__ Bh, unsigned short* __restrict__ Bl) {
    int t = blockIdx.x * 256 + threadIdx.x;
    if (t >= NG * (KG / 8)) return;
    int n = t / (KG / 8), seg = t % (KG / 8);
    int b = n / 36, xy = n % 36;
    int oy = xy / 6, ox = xy % 6;
    const float* hb = h + (size_t)b * (AA * 196) + (2 * oy) * 14 + 2 * ox;
    alignas(16) unsigned short hi[8], lo[8];
#pragma unroll
    for (int j = 0; j < 8; ++j) {
        int k = seg * 8 + j;
        int ic = k / 9, kk = k - ic * 9;
        int ky = kk / 3, kx = kk - ky * 3;
        float v = hb[ic * 196 + ky * 14 + kx];
        v = fmaxf(fmaf(v, bn1[ic], bn1[AA + ic]), 0.f);
        unsigned short hh = f2bf(v);
        hi[j] = hh;
        lo[j] = f2bf(v - bf2f(hh));
    }
    *reinterpret_cast<uint4*>(Bh + (size_t)n * KG + seg * 8) = *reinterpret_cast<const uint4*>(hi);
    *reinterpret_cast<uint4*>(Bl + (size_t)n * KG + seg * 8) = *reinterpret_cast<const uint4*>(lo);
}

// ---------------- conv2 as split-bf16 MFMA GEMM, XCD-swizzled 64x64 tiles -------------
// 648 blocks. Swizzle: same-y (same B-tile) groups of 9 land on one XCD's L2.
__global__ __launch_bounds__(256, 4) void k_gemm(const unsigned short* __restrict__ Ah,
                                                 const unsigned short* __restrict__ Al,
                                                 const unsigned short* __restrict__ Bh,
                                                 const unsigned short* __restrict__ Bl,
                                                 float* __restrict__ pcT) {
    __shared__ alignas(16) unsigned short sAh[64][44], sAl[64][44];
    __shared__ alignas(16) unsigned short sBh[64][44], sBl[64][44];
    // swizzle: s -> xcd k8 = s&7, j = s>>3; y = k8 + 8*(j/9); x = j%9
    const int s = blockIdx.x;
    const int k8 = s & 7, j = s >> 3;
    const int jm = j / 9;
    const int y = k8 + 8 * jm;
    const int xg = j - 9 * jm;
    const int oc0 = xg * 64;
    const int n0 = y * 64;
    const int tid = threadIdx.x;
    const int lane = tid & 63, wv = tid >> 6;
    const int wm = wv >> 1, wn = wv & 1;
    const int quad = lane >> 4, r16 = lane & 15;
    const int srow = tid >> 2, sseg = tid & 3;

    facc4 acc[2][2] = {};
    const size_t gA = (size_t)(oc0 + srow) * KG + sseg * 8;
    const size_t gB = (size_t)(n0 + srow) * KG + sseg * 8;

    for (int ks = 0; ks < KG / 32; ++ks) {
        const int k0 = ks * 32;
        uint4 vAh = *reinterpret_cast<const uint4*>(Ah + gA + k0);
        uint4 vAl = *reinterpret_cast<const uint4*>(Al + gA + k0);
        uint4 vBh = *reinterpret_cast<const uint4*>(Bh + gB + k0);
        uint4 vBl = *reinterpret_cast<const uint4*>(Bl + gB + k0);
        __syncthreads();
        *reinterpret_cast<uint4*>(&sAh[srow][sseg * 8]) = vAh;
        *reinterpret_cast<uint4*>(&sAl[srow][sseg * 8]) = vAl;
        *reinterpret_cast<uint4*>(&sBh[srow][sseg * 8]) = vBh;
        *reinterpret_cast<uint4*>(&sBl[srow][sseg * 8]) = vBl;
        __syncthreads();
        bfrag8 ah[2], al[2], bh[2], bl[2];
#pragma unroll
        for (int i = 0; i < 2; ++i) {
            ah[i] = *reinterpret_cast<const bfrag8*>(&sAh[wm * 32 + i * 16 + r16][quad * 8]);
            al[i] = *reinterpret_cast<const bfrag8*>(&sAl[wm * 32 + i * 16 + r16][quad * 8]);
            bh[i] = *reinterpret_cast<const bfrag8*>(&sBh[wn * 32 + i * 16 + r16][quad * 8]);
            bl[i] = *reinterpret_cast<const bfrag8*>(&sBl[wn * 32 + i * 16 + r16][quad * 8]);
        }
#pragma unroll
        for (int i = 0; i < 2; ++i)
#pragma unroll
            for (int jj = 0; jj < 2; ++jj) {
                acc[i][jj] = __builtin_amdgcn_mfma_f32_16x16x32_bf16(ah[i], bh[jj], acc[i][jj], 0, 0, 0);
                acc[i][jj] = __builtin_amdgcn_mfma_f32_16x16x32_bf16(ah[i], bl[jj], acc[i][jj], 0, 0, 0);
                acc[i][jj] = __builtin_amdgcn_mfma_f32_16x16x32_bf16(al[i], bh[jj], acc[i][jj], 0, 0, 0);
            }
    }
#pragma unroll
    for (int i = 0; i < 2; ++i) {
        int oc_base = oc0 + wm * 32 + i * 16 + quad * 4;
        if (oc_base >= CH2) continue;
#pragma unroll
        for (int jj = 0; jj < 2; ++jj) {
            int n = n0 + wn * 32 + jj * 16 + r16;
            *reinterpret_cast<facc4*>(pcT + (size_t)n * CH2 + oc_base) = acc[i][jj];
        }
    }
}

// ---------------- bn stats on pcT[n][oc] ----------------
__global__ void k_bnstats2(const float* __restrict__ pcT,
                           const float* __restrict__ bna_g, const float* __restrict__ bna_b,
                           const float* __restrict__ bnp_g, const float* __restrict__ bnp_b,
                           float* __restrict__ bn2) {
    int blk = blockIdx.x;
    int tid = threadIdx.x;
    float s = 0.f, s2 = 0.f;
    if (blk < 32) {
        int i = blk;
        for (int j = tid; j < NG * 4; j += 256) {
            int row = j >> 2, q = j & 3;
            float4 v = *reinterpret_cast<const float4*>(pcT + (size_t)row * CH2 + i * 16 + q * 4);
            s += v.x + v.y + v.z + v.w;
            s2 += v.x * v.x + v.y * v.y + v.z * v.z + v.w * v.w;
        }
    } else {
        int i = blk - 32;
        for (int j = tid; j < NG; j += 256) {
            float v = pcT[(size_t)j * CH2 + BB * DD + i];
            s += v; s2 += v * v;
        }
    }
#pragma unroll
    for (int o = 32; o > 0; o >>= 1) { s += __shfl_down(s, o); s2 += __shfl_down(s2, o); }
    __shared__ float ls[4], lq[4];
    int lane = tid & 63, wid = tid >> 6;
    if (lane == 0) { ls[wid] = s; lq[wid] = s2; }
    __syncthreads();
    if (tid == 0) {
        s = ls[0] + ls[1] + ls[2] + ls[3];
        s2 = lq[0] + lq[1] + lq[2] + lq[3];
        if (blk < 32) {
            int i = blk;
            const float n = (float)(NB * DD * 36);
            float mu = s / n, var = s2 / n - mu * mu;
            float sc = bnp_g[i] * rsqrtf(var + 1e-5f);
            bn2[i] = sc; bn2[32 + i] = bnp_b[i] - mu * sc;
        } else {
            int i = blk - 32;
            const float n = (float)(NB * 36);
            float mu = s / n, var = s2 / n - mu * mu;
            float sc = bna_g[i] * rsqrtf(var + 1e-5f);
            bn2[64 + i] = sc; bn2[96 + i] = bna_b[i] - mu * sc;
        }
    }
}

// ---------------- transform: pcT -> poses_bn (b,n,16) and a_i (b,n) ----------------
__global__ void k_transform(const float* __restrict__ pcT, const float* __restrict__ bn2,
                            float* __restrict__ pose, float* __restrict__ ai) {
    int idx = blockIdx.x * 256 + threadIdx.x;
    if (idx >= NB * NN) return;
    int b = idx / NN, n = idx % NN;
    int i = n / 36, xy = n % 36;
    int row = b * 36 + xy;
    float sc = bn2[i], sh = bn2[32 + i];
    const float* src = pcT + (size_t)row * CH2 + i * 16;
    float* pd = pose + (size_t)idx * 16;
#pragma unroll
    for (int q = 0; q < 4; ++q) {
        float4 v = *reinterpret_cast<const float4*>(src + q * 4);
        v.x = fmaf(v.x, sc, sh); v.y = fmaf(v.y, sc, sh);
        v.z = fmaf(v.z, sc, sh); v.w = fmaf(v.w, sc, sh);
        *reinterpret_cast<float4*>(pd + q * 4) = v;
    }
    float va = fmaf(pcT[(size_t)row * CH2 + BB * DD + i], bn2[64 + i], bn2[96 + i]);
    ai[idx] = 1.f / (1.f + expf(-va));
}

// ---------------- merged routing: R-update (softmax over c) + VB stats in one pass ----
// grid 256: block = (b = blk>>1, half = blk&1). 640 threads = 10 waves; wave c owns
// class c. Per (b,n): V computed ONCE, lnp exchanged via LDS for cross-c softmax,
// stats accumulated immediately. R never touches memory. FIRST: wgt = 0.1*a.
template <int FIRST>
__global__ __launch_bounds__(640) void k_routed(
    const float* __restrict__ pose, const float* __restrict__ ai,
    const float* __restrict__ Wij, const float* __restrict__ m,
    const float* __restrict__ G, const float* __restrict__ base,
    float* __restrict__ S0p, float* __restrict__ S1p, float* __restrict__ S2p) {
    const int b = blockIdx.x >> 1, half = blockIdx.x & 1;
    const int tid = threadIdx.x;
    const int c = tid >> 6, lane = tid & 63;
    __shared__ float sLnp[2][CC][65];
    float mc[16], Gc[16], basec = 0.f;
    if (!FIRST) {
        int bc16 = (b * CC + c) * 16;
#pragma unroll
        for (int d = 0; d < 16; ++d) { mc[d] = m[bc16 + d]; Gc[d] = G[bc16 + d]; }
        basec = base[b * CC + c];
    }
    float s0 = 0.f, s1[16], s2[16];
#pragma unroll
    for (int d = 0; d < 16; ++d) { s1[d] = 0.f; s2[d] = 0.f; }

#pragma unroll 1
    for (int it = 0; it < 9; ++it) {
        const int n = half * 576 + it * 64 + lane;
        const int i = n / 36, xy = n - (n / 36) * 36;
        const float4* pp = reinterpret_cast<const float4*>(pose + ((size_t)b * NN + n) * 16);
        const float4* wp = reinterpret_cast<const float4*>(Wij + (((size_t)i * CC + c) * 36 + xy) * 16);
        alignas(16) float P[16], W[16];
        *reinterpret_cast<float4*>(&P[0])  = pp[0];
        *reinterpret_cast<float4*>(&P[4])  = pp[1];
        *reinterpret_cast<float4*>(&P[8])  = pp[2];
        *reinterpret_cast<float4*>(&P[12]) = pp[3];
        *reinterpret_cast<float4*>(&W[0])  = wp[0];
        *reinterpret_cast<float4*>(&W[4])  = wp[1];
        *reinterpret_cast<float4*>(&W[8])  = wp[2];
        *reinterpret_cast<float4*>(&W[12]) = wp[3];
        float V[16];
#pragma unroll
        for (int p = 0; p < 4; ++p)
#pragma unroll
            for (int r = 0; r < 4; ++r)
                V[p * 4 + r] = W[p * 4 + 0] * P[0 + r] + W[p * 4 + 1] * P[4 + r] +
                               W[p * 4 + 2] * P[8 + r] + W[p * 4 + 3] * P[12 + r];
        float av = ai[b * NN + n];
        float wgt;
        if (FIRST) {
            wgt = 0.1f * av;
        } else {
            float q = 0.f;
#pragma unroll
            for (int d = 0; d < 16; ++d) {
                float dm = V[d] - mc[d];
                q = fmaf(dm * dm, Gc[d], q);
            }
            float lnp = basec - q;
            sLnp[it & 1][c][lane] = lnp;
            __syncthreads();
            float mx = -1e30f;
#pragma unroll
            for (int cc = 0; cc < CC; ++cc) mx = fmaxf(mx, sLnp[it & 1][cc][lane]);
            float ssum = 0.f;
#pragma unroll
            for (int cc = 0; cc < CC; ++cc) ssum += expf(sLnp[it & 1][cc][lane] - mx);
            wgt = expf(lnp - mx) / ssum * av;
        }
        s0 += wgt;
#pragma unroll
        for (int d = 0; d < 16; ++d) {
            float wv = wgt * V[d];
            s1[d] += wv;
            s2[d] = fmaf(wv, V[d], s2[d]);
        }
    }
    // wave-level reduce of 33 values
#pragma unroll
    for (int o = 32; o > 0; o >>= 1) {
        s0 += __shfl_down(s0, o);
#pragma unroll
        for (int k = 0; k < 16; ++k) {
            s1[k] += __shfl_down(s1[k], o);
            s2[k] += __shfl_down(s2[k], o);
        }
    }
    if (lane == 0) {
        int idx = half * (NB * CC) + b * CC + c;
        S0p[idx] = s0;
#pragma unroll
        for (int k = 0; k < 16; ++k) { S1p[idx * 16 + k] = s1[k]; S2p[idx * 16 + k] = s2[k]; }
    }
}

// ---------------- digamma (args always >= 1.0 here) ----------------
__device__ __forceinline__ float digammaf_(float x) {
    float r = 0.f;
    while (x < 6.f) { r -= 1.f / x; x += 1.f; }
    float xi = 1.f / x;
    float xi2 = xi * xi;
    return r + logf(x) - 0.5f * xi -
           xi2 * (0.0833333333f - xi2 * (0.0083333333f - xi2 * 0.0039682540f));
}

// ---------------- expectations (sums the 2 half-partials) ----------------
template <int LOGITS>
__global__ void k_expect(const float* __restrict__ S0p, const float* __restrict__ S1p,
                         const float* __restrict__ S2p, float* __restrict__ m,
                         float* __restrict__ G, float* __restrict__ base,
                         float* __restrict__ logits) {
    int b = blockIdx.x;
    int c = threadIdx.x;
    __shared__ float alph[CC];
    float njraw = 0.f;
    if (c < CC) {
        njraw = S0p[b * CC + c] + S0p[NB * CC + b * CC + c];
        alph[c] = 1.f + njraw + 1e-8f;
    }
    __syncthreads();
    if (c < CC) {
        int bc = b * CC + c;
        float nj = njraw + 1e-8f;
        float asum = 0.f;
#pragma unroll
        for (int k = 0; k < CC; ++k) asum += alph[k];
        float kappa = 1.f + nj;
        float nu = 17.f + nj;
        float S0 = njraw;
        float elnlam = 16.f * 0.69314718056f;
        for (int d = 0; d < 16; ++d) {
            float s1 = S1p[bc * 16 + d] + S1p[(NB * CC + bc) * 16 + d];
            float s2v = S2p[bc * 16 + d] + S2p[(NB * CC + bc) * 16 + d];
            float xbar = s1 / nj;
            float sig = (s2v - 2.f * xbar * s1 + xbar * xbar * S0) / nj;
            float Psi = 1.f + nj * sig + (nj / kappa) * xbar * xbar;
            elnlam += digammaf_(0.5f * (nu + 1.f - (float)(d + 1))) - logf(Psi);
            m[bc * 16 + d] = nj * xbar / kappa;
            G[bc * 16 + d] = 0.5f * nu / Psi;
        }
        float elnpi = digammaf_(1.f + nj) - digammaf_(asum);
        float lb = elnpi + 0.5f * elnlam;
        if (LOGITS) logits[bc] = lb;
        base[bc] = lb - 8.f * 1.83787706641f - 8.f / kappa;
    }
}

// ---------------- final: BN over batch per class + sigmoid ----------------
__global__ void k_final(const float* __restrict__ logits, float* __restrict__ out) {
    int c = blockIdx.x;
    int b = threadIdx.x;
    float v = logits[b * CC + c];
    float s = v, s2 = v * v;
#pragma unroll
    for (int o = 32; o > 0; o >>= 1) { s += __shfl_down(s, o); s2 += __shfl_down(s2, o); }
    __shared__ float ls[2], lq[2];
    int lane = b & 63, wid = b >> 6;
    if (lane == 0) { ls[wid] = s; lq[wid] = s2; }
    __syncthreads();
    float mu = (ls[0] + ls[1]) * (1.f / 128.f);
    float var = (lq[0] + lq[1]) * (1.f / 128.f) - mu * mu;
    out[b * CC + c] = 1.f / (1.f + expf(-(v - mu) * rsqrtf(var + 1e-5f)));
}

extern "C" void kernel_launch(void* const* d_in, const int* in_sizes, int n_in,
                              void* d_out, int out_size, void* d_ws, size_t ws_size,
                              hipStream_t stream) {
    (void)in_sizes; (void)n_in; (void)out_size; (void)ws_size;
    const float* x       = (const float*)d_in[0];
    const float* conv1_w = (const float*)d_in[1];
    const float* bn1_g   = (const float*)d_in[2];
    const float* bn1_b   = (const float*)d_in[3];
    const float* prim_w  = (const float*)d_in[4];
    const float* bna_g   = (const float*)d_in[5];
    const float* bna_b   = (const float*)d_in[6];
    const float* bnp_g   = (const float*)d_in[7];
    const float* bnp_b   = (const float*)d_in[8];
    const float* Wij     = (const float*)d_in[9];

    float* ws = (float*)d_ws;
    float* h   = ws;                                          // 3,211,264 f32
    float* pcT = ws + 3211264;                                // 2,506,752 f32 [4608][544]
    unsigned short* Bh = (unsigned short*)(ws + 5718016);     // 5,308,416 bf16
    unsigned short* Bl = (unsigned short*)(ws + 8372224);     // 5,308,416 bf16
    unsigned short* Ahp = (unsigned short*)(ws + 11026432);   //   663,552 bf16
    unsigned short* Alp = (unsigned short*)(ws + 11358208);   //   663,552 bf16
    float* bn1    = ws + 11689984;   // 256
    float* bn2    = ws + 11690240;   // 128
    float* S0p    = ws + 11690368;   // 2,560 (2 halves x 1280)
    float* S1p    = ws + 11692928;   // 40,960
    float* S2p    = ws + 11733888;   // 40,960
    float* m      = ws + 11774848;   // 20,480
    float* G      = ws + 11795328;   // 20,480
    float* base   = ws + 11815808;   // 1,280
    float* logits = ws + 11817088;   // 1,280
    // Aliases: Bh/Bl are dead after k_gemm; pose/ai reuse their space. R is gone.
    float* pose = ws + 5718016;      // 2,359,296 f32 (inside Bh region)
    float* ai   = ws + 8372224;      //   147,456 f32 (inside Bl region)
    float* out  = (float*)d_out;

    k_conv1<<<dim3(7, 128), 256, 0, stream>>>(x, conv1_w, h);
    k_bnstats1<<<128, 256, 0, stream>>>(h, bn1_g, bn1_b, bn1);
    k_prepw<<<324, 256, 0, stream>>>(prim_w, Ahp, Alp);
    k_im2col<<<2592, 256, 0, stream>>>(h, bn1, Bh, Bl);
    k_gemm<<<648, 256, 0, stream>>>(Ahp, Alp, Bh, Bl, pcT);
    k_bnstats2<<<64, 256, 0, stream>>>(pcT, bna_g, bna_b, bnp_g, bnp_b, bn2);
    k_transform<<<576, 256, 0, stream>>>(pcT, bn2, pose, ai);

    // routing: iter0 stats (R = 1/C), then 2x (expect -> merged update+stats), final expect
    k_routed<1><<<256, 640, 0, stream>>>(pose, ai, Wij, m, G, base, S0p, S1p, S2p);
    k_expect<0><<<128, 64, 0, stream>>>(S0p, S1p, S2p, m, G, base, logits);
    k_routed<0><<<256, 640, 0, stream>>>(pose, ai, Wij, m, G, base, S0p, S1p, S2p);
    k_expect<0><<<128, 64, 0, stream>>>(S0p, S1p, S2p, m, G, base, logits);
    k_routed<0><<<256, 640, 0, stream>>>(pose, ai, Wij, m, G, base, S0p, S1p, S2p);
    k_expect<1><<<128, 64, 0, stream>>>(S0p, S1p, S2p, m, G, base, logits);

    k_final<<<10, 128, 0, stream>>>(logits, out);
}

// Round 12
// 215.705 us; speedup vs baseline: 1.4521x; 1.1518x over previous
//
#include <hip/hip_runtime.h>
#include <hip/hip_bf16.h>

// Problem constants
#define NB 128     // batch
#define AA 128     // conv1 out channels
#define BB 32      // capsule types
#define CC 10      // classes
#define KK 6       // primary grid
#define DD 16      // pose dim
#define NN 1152    // B*K*K
#define H1 14      // conv1 out spatial
#define CH2 544    // B*D+B
#define NG 4608    // GEMM N = NB*36
#define KG 1152    // GEMM K = 128*9
#define MG 576     // GEMM M padded (544 -> 9*64)

typedef short bfrag8 __attribute__((ext_vector_type(8)));   // 8 bf16 (4 VGPRs)
typedef float facc4 __attribute__((ext_vector_type(4)));    // 4 fp32 acc

__device__ __forceinline__ unsigned short f2bf(float f) {   // RNE f32->bf16
    unsigned u = __float_as_uint(f);
    u += 0x7FFF + ((u >> 16) & 1);
    return (unsigned short)(u >> 16);
}
__device__ __forceinline__ float bf2f(unsigned short s) {
    return __uint_as_float(((unsigned)s) << 16);
}

// ---------------- conv1 (LDS-staged): (128,3,32,32) -> (128,128,14,14), 5x5 s2 --------
__global__ __launch_bounds__(256, 3) void k_conv1(const float* __restrict__ x,
                                                  const float* __restrict__ w,
                                                  float* __restrict__ h) {
    __shared__ __align__(16) float sX[3][7][32];   //  2,688 B
    __shared__ float sWf[AA * 75];                 // 38,400 B
    const int p = blockIdx.x;
    const int b = blockIdx.y;
    const int tid = threadIdx.x;
    for (int j = tid; j < AA * 75; j += 256) sWf[j] = w[j];
    for (int j = tid; j < 3 * 7 * 32; j += 256) {
        int col = j & 31; int t2 = j >> 5; int row = t2 % 7; int ic = t2 / 7;
        sX[ic][row][col] = x[b * 3072 + ic * 1024 + (4 * p + row) * 32 + col];
    }
    __syncthreads();
    const int oc = tid & 127, ry = tid >> 7;
    const int r = 2 * p + ry;
    float acc[14];
#pragma unroll
    for (int j = 0; j < 14; ++j) acc[j] = 0.f;
    const float* wr = sWf + oc * 75;
#pragma unroll
    for (int ic = 0; ic < 3; ++ic) {
#pragma unroll
        for (int ky = 0; ky < 5; ++ky) {
            const float* xr = &sX[ic][2 * ry + ky][0];
            float row[32];
#pragma unroll
            for (int q = 0; q < 8; ++q) {
                float4 v = *reinterpret_cast<const float4*>(xr + q * 4);
                row[q * 4 + 0] = v.x; row[q * 4 + 1] = v.y;
                row[q * 4 + 2] = v.z; row[q * 4 + 3] = v.w;
            }
            float w0 = wr[ic * 25 + ky * 5 + 0];
            float w1 = wr[ic * 25 + ky * 5 + 1];
            float w2 = wr[ic * 25 + ky * 5 + 2];
            float w3 = wr[ic * 25 + ky * 5 + 3];
            float w4 = wr[ic * 25 + ky * 5 + 4];
#pragma unroll
            for (int ox = 0; ox < 14; ++ox) {
                float s = acc[ox];
                s = fmaf(row[2 * ox + 0], w0, s);
                s = fmaf(row[2 * ox + 1], w1, s);
                s = fmaf(row[2 * ox + 2], w2, s);
                s = fmaf(row[2 * ox + 3], w3, s);
                s = fmaf(row[2 * ox + 4], w4, s);
                acc[ox] = s;
            }
        }
    }
    float* out = h + ((size_t)(b * AA + oc) * 14 + r) * 14;
#pragma unroll
    for (int q = 0; q < 7; ++q)
        *reinterpret_cast<float2*>(out + q * 2) = make_float2(acc[q * 2], acc[q * 2 + 1]);
}

// ---------------- block reduce helper (s, s2) ----------------
__device__ __forceinline__ void blk_reduce2(float& s, float& s2, int tid) {
#pragma unroll
    for (int o = 32; o > 0; o >>= 1) { s += __shfl_down(s, o); s2 += __shfl_down(s2, o); }
    __shared__ float ls[4], lq[4];
    int lane = tid & 63, wid = tid >> 6;
    if (lane == 0) { ls[wid] = s; lq[wid] = s2; }
    __syncthreads();
    if (tid == 0) {
        s = ls[0] + ls[1] + ls[2] + ls[3];
        s2 = lq[0] + lq[1] + lq[2] + lq[3];
    }
}

// ---------------- bn1 stats stage A: 1024 blocks, partials [2][128][8] ----------------
__global__ void k_bnstats1a(const float* __restrict__ h, float* __restrict__ part) {
    int c = blockIdx.x & 127, sl = blockIdx.x >> 7;
    int tid = threadIdx.x;
    float s = 0.f, s2 = 0.f;
    for (int j = tid; j < 16 * 196; j += 256) {
        int b = sl * 16 + j / 196, hw = j % 196;
        float v = h[((size_t)b * AA + c) * 196 + hw];
        s += v; s2 += v * v;
    }
    blk_reduce2(s, s2, tid);
    if (tid == 0) { part[c * 8 + sl] = s; part[1024 + c * 8 + sl] = s2; }
}

// ---------------- bn1 finalize: 1 block x 128 ----------------
__global__ void k_bnfin1(const float* __restrict__ part, const float* __restrict__ g,
                         const float* __restrict__ be, float* __restrict__ bn1) {
    int c = threadIdx.x;
    float s = 0.f, s2 = 0.f;
#pragma unroll
    for (int sl = 0; sl < 8; ++sl) { s += part[c * 8 + sl]; s2 += part[1024 + c * 8 + sl]; }
    const float n = (float)(NB * 196);
    float mu = s / n;
    float var = s2 / n - mu * mu;
    float sc = g[c] * rsqrtf(var + 1e-5f);
    bn1[c] = sc;
    bn1[AA + c] = be[c] - mu * sc;
}

// ---------------- prep weights: prim_w [544][1152] f32 -> Ah/Al [576][1152] bf16 ------
__global__ void k_prepw(const float* __restrict__ w, unsigned short* __restrict__ Ah,
                        unsigned short* __restrict__ Al) {
    int t = blockIdx.x * 256 + threadIdx.x;
    if (t >= MG * (KG / 8)) return;
    int row = t / (KG / 8), seg = t % (KG / 8);
    alignas(16) unsigned short hi[8], lo[8];
    if (row < CH2) {
        const float* src = w + (size_t)row * KG + seg * 8;
#pragma unroll
        for (int j = 0; j < 8; ++j) {
            float v = src[j];
            unsigned short hh = f2bf(v);
            hi[j] = hh;
            lo[j] = f2bf(v - bf2f(hh));
        }
    } else {
#pragma unroll
        for (int j = 0; j < 8; ++j) { hi[j] = 0; lo[j] = 0; }
    }
    *reinterpret_cast<uint4*>(Ah + (size_t)row * KG + seg * 8) = *reinterpret_cast<const uint4*>(hi);
    *reinterpret_cast<uint4*>(Al + (size_t)row * KG + seg * 8) = *reinterpret_cast<const uint4*>(lo);
}

// ---------------- im2col + fused bn1+relu: h -> Bh/Bl [4608][1152] bf16 ---------------
__global__ void k_im2col(const float* __restrict__ h, const float* __restrict__ bn1,
                         unsigned short* __restrict__ Bh, unsigned short* __restrict__ Bl) {
    int t = blockIdx.x * 256 + threadIdx.x;
    if (t >= NG * (KG / 8)) return;
    int n = t / (KG / 8), seg = t % (KG / 8);
    int b = n / 36, xy = n % 36;
    int oy = xy / 6, ox = xy % 6;
    const float* hb = h + (size_t)b * (AA * 196) + (2 * oy) * 14 + 2 * ox;
    alignas(16) unsigned short hi[8], lo[8];
#pragma unroll
    for (int j = 0; j < 8; ++j) {
        int k = seg * 8 + j;
        int ic = k / 9, kk = k - ic * 9;
        int ky = kk / 3, kx = kk - ky * 3;
        float v = hb[ic * 196 + ky * 14 + kx];
        v = fmaxf(fmaf(v, bn1[ic], bn1[AA + ic]), 0.f);
        unsigned short hh = f2bf(v);
        hi[j] = hh;
        lo[j] = f2bf(v - bf2f(hh));
    }
    *reinterpret_cast<uint4*>(Bh + (size_t)n * KG + seg * 8) = *reinterpret_cast<const uint4*>(hi);
    *reinterpret_cast<uint4*>(Bl + (size_t)n * KG + seg * 8) = *reinterpret_cast<const uint4*>(lo);
}

// ---------------- conv2 as split-bf16 MFMA GEMM, XCD-swizzled 64x64 tiles -------------
__global__ __launch_bounds__(256, 4) void k_gemm(const unsigned short* __restrict__ Ah,
                                                 const unsigned short* __restrict__ Al,
                                                 const unsigned short* __restrict__ Bh,
                                                 const unsigned short* __restrict__ Bl,
                                                 float* __restrict__ pcT) {
    __shared__ alignas(16) unsigned short sAh[64][44], sAl[64][44];
    __shared__ alignas(16) unsigned short sBh[64][44], sBl[64][44];
    const int s = blockIdx.x;
    const int k8 = s & 7, j = s >> 3;
    const int jm = j / 9;
    const int y = k8 + 8 * jm;
    const int xg = j - 9 * jm;
    const int oc0 = xg * 64;
    const int n0 = y * 64;
    const int tid = threadIdx.x;
    const int lane = tid & 63, wv = tid >> 6;
    const int wm = wv >> 1, wn = wv & 1;
    const int quad = lane >> 4, r16 = lane & 15;
    const int srow = tid >> 2, sseg = tid & 3;

    facc4 acc[2][2] = {};
    const size_t gA = (size_t)(oc0 + srow) * KG + sseg * 8;
    const size_t gB = (size_t)(n0 + srow) * KG + sseg * 8;

    for (int ks = 0; ks < KG / 32; ++ks) {
        const int k0 = ks * 32;
        uint4 vAh = *reinterpret_cast<const uint4*>(Ah + gA + k0);
        uint4 vAl = *reinterpret_cast<const uint4*>(Al + gA + k0);
        uint4 vBh = *reinterpret_cast<const uint4*>(Bh + gB + k0);
        uint4 vBl = *reinterpret_cast<const uint4*>(Bl + gB + k0);
        __syncthreads();
        *reinterpret_cast<uint4*>(&sAh[srow][sseg * 8]) = vAh;
        *reinterpret_cast<uint4*>(&sAl[srow][sseg * 8]) = vAl;
        *reinterpret_cast<uint4*>(&sBh[srow][sseg * 8]) = vBh;
        *reinterpret_cast<uint4*>(&sBl[srow][sseg * 8]) = vBl;
        __syncthreads();
        bfrag8 ah[2], al[2], bh[2], bl[2];
#pragma unroll
        for (int i = 0; i < 2; ++i) {
            ah[i] = *reinterpret_cast<const bfrag8*>(&sAh[wm * 32 + i * 16 + r16][quad * 8]);
            al[i] = *reinterpret_cast<const bfrag8*>(&sAl[wm * 32 + i * 16 + r16][quad * 8]);
            bh[i] = *reinterpret_cast<const bfrag8*>(&sBh[wn * 32 + i * 16 + r16][quad * 8]);
            bl[i] = *reinterpret_cast<const bfrag8*>(&sBl[wn * 32 + i * 16 + r16][quad * 8]);
        }
#pragma unroll
        for (int i = 0; i < 2; ++i)
#pragma unroll
            for (int jj = 0; jj < 2; ++jj) {
                acc[i][jj] = __builtin_amdgcn_mfma_f32_16x16x32_bf16(ah[i], bh[jj], acc[i][jj], 0, 0, 0);
                acc[i][jj] = __builtin_amdgcn_mfma_f32_16x16x32_bf16(ah[i], bl[jj], acc[i][jj], 0, 0, 0);
                acc[i][jj] = __builtin_amdgcn_mfma_f32_16x16x32_bf16(al[i], bh[jj], acc[i][jj], 0, 0, 0);
            }
    }
#pragma unroll
    for (int i = 0; i < 2; ++i) {
        int oc_base = oc0 + wm * 32 + i * 16 + quad * 4;
        if (oc_base >= CH2) continue;
#pragma unroll
        for (int jj = 0; jj < 2; ++jj) {
            int n = n0 + wn * 32 + jj * 16 + r16;
            *reinterpret_cast<facc4*>(pcT + (size_t)n * CH2 + oc_base) = acc[i][jj];
        }
    }
}

// ---------------- bn2 stats stage A: 320 blocks ----------------
// part layout: [0..255] pose s, [256..511] pose s2, [512..575] a s, [576..639] a s2
__global__ void k_bnstats2a(const float* __restrict__ pcT, float* __restrict__ part) {
    int blk = blockIdx.x, tid = threadIdx.x;
    float s = 0.f, s2 = 0.f;
    if (blk < 256) {
        int i = blk >> 3, sl = blk & 7;
        for (int j = tid; j < 576 * 4; j += 256) {
            int row = sl * 576 + (j >> 2), q = j & 3;
            float4 v = *reinterpret_cast<const float4*>(pcT + (size_t)row * CH2 + i * 16 + q * 4);
            s += v.x + v.y + v.z + v.w;
            s2 += v.x * v.x + v.y * v.y + v.z * v.z + v.w * v.w;
        }
        blk_reduce2(s, s2, tid);
        if (tid == 0) { part[blk] = s; part[256 + blk] = s2; }
    } else {
        int t2 = blk - 256;
        int ch = t2 >> 1, sl = t2 & 1;
        for (int j = tid; j < 2304; j += 256) {
            int row = sl * 2304 + j;
            float v = pcT[(size_t)row * CH2 + BB * DD + ch];
            s += v; s2 += v * v;
        }
        blk_reduce2(s, s2, tid);
        if (tid == 0) { part[512 + t2] = s; part[576 + t2] = s2; }
    }
}

// ---------------- bn2 finalize: 1 block x 64 ----------------
__global__ void k_bnfin2(const float* __restrict__ part,
                         const float* __restrict__ bna_g, const float* __restrict__ bna_b,
                         const float* __restrict__ bnp_g, const float* __restrict__ bnp_b,
                         float* __restrict__ bn2) {
    int t = threadIdx.x;
    if (t < 32) {
        float s = 0.f, s2 = 0.f;
#pragma unroll
        for (int sl = 0; sl < 8; ++sl) { s += part[t * 8 + sl]; s2 += part[256 + t * 8 + sl]; }
        const float n = (float)(NB * DD * 36);
        float mu = s / n, var = s2 / n - mu * mu;
        float sc = bnp_g[t] * rsqrtf(var + 1e-5f);
        bn2[t] = sc; bn2[32 + t] = bnp_b[t] - mu * sc;
    } else {
        int ch = t - 32;
        float s = part[512 + ch * 2] + part[512 + ch * 2 + 1];
        float s2 = part[576 + ch * 2] + part[576 + ch * 2 + 1];
        const float n = (float)(NB * 36);
        float mu = s / n, var = s2 / n - mu * mu;
        float sc = bna_g[ch] * rsqrtf(var + 1e-5f);
        bn2[64 + ch] = sc; bn2[96 + ch] = bna_b[ch] - mu * sc;
    }
}

// ---------------- merged routing, reads pcT directly (bn2 applied on the fly) ---------
// grid 256: block = (b = blk>>1, half = blk&1). 640 threads = 10 waves; wave c owns
// class c. Per (b,n): pose/a built from pcT+bn2, V computed ONCE, lnp exchanged via
// LDS for the cross-c softmax, stats accumulated immediately. R never touches memory.
template <int FIRST>
__global__ __launch_bounds__(640) void k_routed(
    const float* __restrict__ pcT, const float* __restrict__ bn2,
    const float* __restrict__ Wij, const float* __restrict__ m,
    const float* __restrict__ G, const float* __restrict__ base,
    float* __restrict__ S0p, float* __restrict__ S1p, float* __restrict__ S2p) {
    const int b = blockIdx.x >> 1, half = blockIdx.x & 1;
    const int tid = threadIdx.x;
    const int c = tid >> 6, lane = tid & 63;
    __shared__ float sLnp[2][CC][65];
    __shared__ float sBn2[128];
    if (tid < 128) sBn2[tid] = bn2[tid];
    float mc[16], Gc[16], basec = 0.f;
    if (!FIRST) {
        int bc16 = (b * CC + c) * 16;
#pragma unroll
        for (int d = 0; d < 16; ++d) { mc[d] = m[bc16 + d]; Gc[d] = G[bc16 + d]; }
        basec = base[b * CC + c];
    }
    float s0 = 0.f, s1[16], s2[16];
#pragma unroll
    for (int d = 0; d < 16; ++d) { s1[d] = 0.f; s2[d] = 0.f; }
    __syncthreads();   // sBn2 ready

#pragma unroll 1
    for (int it = 0; it < 9; ++it) {
        const int n = half * 576 + it * 64 + lane;
        const int i = n / 36, xy = n - i * 36;
        const int row = b * 36 + xy;
        const float4* pp = reinterpret_cast<const float4*>(pcT + (size_t)row * CH2 + i * 16);
        const float4* wp = reinterpret_cast<const float4*>(Wij + (((size_t)i * CC + c) * 36 + xy) * 16);
        alignas(16) float P[16], W[16];
        *reinterpret_cast<float4*>(&P[0])  = pp[0];
        *reinterpret_cast<float4*>(&P[4])  = pp[1];
        *reinterpret_cast<float4*>(&P[8])  = pp[2];
        *reinterpret_cast<float4*>(&P[12]) = pp[3];
        *reinterpret_cast<float4*>(&W[0])  = wp[0];
        *reinterpret_cast<float4*>(&W[4])  = wp[1];
        *reinterpret_cast<float4*>(&W[8])  = wp[2];
        *reinterpret_cast<float4*>(&W[12]) = wp[3];
        const float psc = sBn2[i], psh = sBn2[32 + i];
#pragma unroll
        for (int d = 0; d < 16; ++d) P[d] = fmaf(P[d], psc, psh);
        float V[16];
#pragma unroll
        for (int p = 0; p < 4; ++p)
#pragma unroll
            for (int r = 0; r < 4; ++r)
                V[p * 4 + r] = W[p * 4 + 0] * P[0 + r] + W[p * 4 + 1] * P[4 + r] +
                               W[p * 4 + 2] * P[8 + r] + W[p * 4 + 3] * P[12 + r];
        float va = fmaf(pcT[(size_t)row * CH2 + BB * DD + i], sBn2[64 + i], sBn2[96 + i]);
        float av = 1.f / (1.f + expf(-va));
        float wgt;
        if (FIRST) {
            wgt = 0.1f * av;
        } else {
            float q = 0.f;
#pragma unroll
            for (int d = 0; d < 16; ++d) {
                float dm = V[d] - mc[d];
                q = fmaf(dm * dm, Gc[d], q);
            }
            float lnp = basec - q;
            sLnp[it & 1][c][lane] = lnp;
            __syncthreads();
            float mx = -1e30f;
#pragma unroll
            for (int cc = 0; cc < CC; ++cc) mx = fmaxf(mx, sLnp[it & 1][cc][lane]);
            float ssum = 0.f;
#pragma unroll
            for (int cc = 0; cc < CC; ++cc) ssum += expf(sLnp[it & 1][cc][lane] - mx);
            wgt = expf(lnp - mx) / ssum * av;
        }
        s0 += wgt;
#pragma unroll
        for (int d = 0; d < 16; ++d) {
            float wv = wgt * V[d];
            s1[d] += wv;
            s2[d] = fmaf(wv, V[d], s2[d]);
        }
    }
    // wave-level reduce of 33 values
#pragma unroll
    for (int o = 32; o > 0; o >>= 1) {
        s0 += __shfl_down(s0, o);
#pragma unroll
        for (int k = 0; k < 16; ++k) {
            s1[k] += __shfl_down(s1[k], o);
            s2[k] += __shfl_down(s2[k], o);
        }
    }
    if (lane == 0) {
        int idx = half * (NB * CC) + b * CC + c;
        S0p[idx] = s0;
#pragma unroll
        for (int k = 0; k < 16; ++k) { S1p[idx * 16 + k] = s1[k]; S2p[idx * 16 + k] = s2[k]; }
    }
}

// ---------------- digamma (args always >= 1.0 here) ----------------
__device__ __forceinline__ float digammaf_(float x) {
    float r = 0.f;
    while (x < 6.f) { r -= 1.f / x; x += 1.f; }
    float xi = 1.f / x;
    float xi2 = xi * xi;
    return r + logf(x) - 0.5f * xi -
           xi2 * (0.0833333333f - xi2 * (0.0083333333f - xi2 * 0.0039682540f));
}

// ---------------- expectations (sums the 2 half-partials) ----------------
template <int LOGITS>
__global__ void k_expect(const float* __restrict__ S0p, const float* __restrict__ S1p,
                         const float* __restrict__ S2p, float* __restrict__ m,
                         float* __restrict__ G, float* __restrict__ base,
                         float* __restrict__ logits) {
    int b = blockIdx.x;
    int c = threadIdx.x;
    __shared__ float alph[CC];
    float njraw = 0.f;
    if (c < CC) {
        njraw = S0p[b * CC + c] + S0p[NB * CC + b * CC + c];
        alph[c] = 1.f + njraw + 1e-8f;
    }
    __syncthreads();
    if (c < CC) {
        int bc = b * CC + c;
        float nj = njraw + 1e-8f;
        float asum = 0.f;
#pragma unroll
        for (int k = 0; k < CC; ++k) asum += alph[k];
        float kappa = 1.f + nj;
        float nu = 17.f + nj;
        float S0 = njraw;
        float elnlam = 16.f * 0.69314718056f;
        for (int d = 0; d < 16; ++d) {
            float s1 = S1p[bc * 16 + d] + S1p[(NB * CC + bc) * 16 + d];
            float s2v = S2p[bc * 16 + d] + S2p[(NB * CC + bc) * 16 + d];
            float xbar = s1 / nj;
            float sig = (s2v - 2.f * xbar * s1 + xbar * xbar * S0) / nj;
            float Psi = 1.f + nj * sig + (nj / kappa) * xbar * xbar;
            elnlam += digammaf_(0.5f * (nu + 1.f - (float)(d + 1))) - logf(Psi);
            m[bc * 16 + d] = nj * xbar / kappa;
            G[bc * 16 + d] = 0.5f * nu / Psi;
        }
        float elnpi = digammaf_(1.f + nj) - digammaf_(asum);
        float lb = elnpi + 0.5f * elnlam;
        if (LOGITS) logits[bc] = lb;
        base[bc] = lb - 8.f * 1.83787706641f - 8.f / kappa;
    }
}

// ---------------- final: BN over batch per class + sigmoid ----------------
__global__ void k_final(const float* __restrict__ logits, float* __restrict__ out) {
    int c = blockIdx.x;
    int b = threadIdx.x;
    float v = logits[b * CC + c];
    float s = v, s2 = v * v;
#pragma unroll
    for (int o = 32; o > 0; o >>= 1) { s += __shfl_down(s, o); s2 += __shfl_down(s2, o); }
    __shared__ float ls[2], lq[2];
    int lane = b & 63, wid = b >> 6;
    if (lane == 0) { ls[wid] = s; lq[wid] = s2; }
    __syncthreads();
    float mu = (ls[0] + ls[1]) * (1.f / 128.f);
    float var = (lq[0] + lq[1]) * (1.f / 128.f) - mu * mu;
    out[b * CC + c] = 1.f / (1.f + expf(-(v - mu) * rsqrtf(var + 1e-5f)));
}

extern "C" void kernel_launch(void* const* d_in, const int* in_sizes, int n_in,
                              void* d_out, int out_size, void* d_ws, size_t ws_size,
                              hipStream_t stream) {
    (void)in_sizes; (void)n_in; (void)out_size; (void)ws_size;
    const float* x       = (const float*)d_in[0];
    const float* conv1_w = (const float*)d_in[1];
    const float* bn1_g   = (const float*)d_in[2];
    const float* bn1_b   = (const float*)d_in[3];
    const float* prim_w  = (const float*)d_in[4];
    const float* bna_g   = (const float*)d_in[5];
    const float* bna_b   = (const float*)d_in[6];
    const float* bnp_g   = (const float*)d_in[7];
    const float* bnp_b   = (const float*)d_in[8];
    const float* Wij     = (const float*)d_in[9];

    float* ws = (float*)d_ws;
    float* h   = ws;                                          // 3,211,264 f32
    float* pcT = ws + 3211264;                                // 2,506,752 f32 [4608][544]
    unsigned short* Bh = (unsigned short*)(ws + 5718016);     // 5,308,416 bf16
    unsigned short* Bl = (unsigned short*)(ws + 8372224);     // 5,308,416 bf16
    unsigned short* Ahp = (unsigned short*)(ws + 11026432);   //   663,552 bf16
    unsigned short* Alp = (unsigned short*)(ws + 11358208);   //   663,552 bf16
    float* bn1    = ws + 11689984;   // 256
    float* bn2    = ws + 11690240;   // 128
    float* S0p    = ws + 11690368;   // 2,560 (2 halves x 1280)
    float* S1p    = ws + 11692928;   // 40,960
    float* S2p    = ws + 11733888;   // 40,960
    float* m      = ws + 11774848;   // 20,480
    float* G      = ws + 11795328;   // 20,480
    float* base   = ws + 11815808;   // 1,280
    float* logits = ws + 11817088;   // 1,280
    float* part1  = ws + 11818368;   // 2,048  (bn1 partials)
    float* part2  = ws + 11820416;   //   640  (bn2 partials)
    float* out    = (float*)d_out;

    k_conv1<<<dim3(7, 128), 256, 0, stream>>>(x, conv1_w, h);
    k_bnstats1a<<<1024, 256, 0, stream>>>(h, part1);
    k_bnfin1<<<1, 128, 0, stream>>>(part1, bn1_g, bn1_b, bn1);
    k_prepw<<<324, 256, 0, stream>>>(prim_w, Ahp, Alp);
    k_im2col<<<2592, 256, 0, stream>>>(h, bn1, Bh, Bl);
    k_gemm<<<648, 256, 0, stream>>>(Ahp, Alp, Bh, Bl, pcT);
    k_bnstats2a<<<320, 256, 0, stream>>>(pcT, part2);
    k_bnfin2<<<1, 64, 0, stream>>>(part2, bna_g, bna_b, bnp_g, bnp_b, bn2);

    // routing: iter0 stats (R = 1/C), then 2x (expect -> merged update+stats), final expect
    k_routed<1><<<256, 640, 0, stream>>>(pcT, bn2, Wij, m, G, base, S0p, S1p, S2p);
    k_expect<0><<<128, 64, 0, stream>>>(S0p, S1p, S2p, m, G, base, logits);
    k_routed<0><<<256, 640, 0, stream>>>(pcT, bn2, Wij, m, G, base, S0p, S1p, S2p);
    k_expect<0><<<128, 64, 0, stream>>>(S0p, S1p, S2p, m, G, base, logits);
    k_routed<0><<<256, 640, 0, stream>>>(pcT, bn2, Wij, m, G, base, S0p, S1p, S2p);
    k_expect<1><<<128, 64, 0, stream>>>(S0p, S1p, S2p, m, G, base, logits);

    k_final<<<10, 128, 0, stream>>>(logits, out);
}

// Round 13
// 188.005 us; speedup vs baseline: 1.6660x; 1.1473x over previous
//
#include <hip/hip_runtime.h>
#include <hip/hip_bf16.h>

// Problem constants
#define NB 128     // batch
#define AA 128     // conv1 out channels
#define BB 32      // capsule types
#define CC 10      // classes
#define KK 6       // primary grid
#define DD 16      // pose dim
#define NN 1152    // B*K*K
#define H1 14      // conv1 out spatial
#define CH2 544    // B*D+B
#define NG 4608    // GEMM N = NB*36
#define KG 1152    // GEMM K = 128*9
#define MG 576     // GEMM M padded (544 -> 9*64)

typedef short bfrag8 __attribute__((ext_vector_type(8)));   // 8 bf16 (4 VGPRs)
typedef float facc4 __attribute__((ext_vector_type(4)));    // 4 fp32 acc

__device__ __forceinline__ unsigned short f2bf(float f) {   // RNE f32->bf16
    unsigned u = __float_as_uint(f);
    u += 0x7FFF + ((u >> 16) & 1);
    return (unsigned short)(u >> 16);
}
__device__ __forceinline__ float bf2f(unsigned short s) {
    return __uint_as_float(((unsigned)s) << 16);
}

// ---------------- conv1 (LDS-staged): (128,3,32,32) -> (128,128,14,14), 5x5 s2 --------
__global__ __launch_bounds__(256, 3) void k_conv1(const float* __restrict__ x,
                                                  const float* __restrict__ w,
                                                  float* __restrict__ h) {
    __shared__ __align__(16) float sX[3][7][32];   //  2,688 B
    __shared__ float sWf[AA * 75];                 // 38,400 B
    const int p = blockIdx.x;
    const int b = blockIdx.y;
    const int tid = threadIdx.x;
    for (int j = tid; j < AA * 75; j += 256) sWf[j] = w[j];
    for (int j = tid; j < 3 * 7 * 32; j += 256) {
        int col = j & 31; int t2 = j >> 5; int row = t2 % 7; int ic = t2 / 7;
        sX[ic][row][col] = x[b * 3072 + ic * 1024 + (4 * p + row) * 32 + col];
    }
    __syncthreads();
    const int oc = tid & 127, ry = tid >> 7;
    const int r = 2 * p + ry;
    float acc[14];
#pragma unroll
    for (int j = 0; j < 14; ++j) acc[j] = 0.f;
    const float* wr = sWf + oc * 75;
#pragma unroll
    for (int ic = 0; ic < 3; ++ic) {
#pragma unroll
        for (int ky = 0; ky < 5; ++ky) {
            const float* xr = &sX[ic][2 * ry + ky][0];
            float row[32];
#pragma unroll
            for (int q = 0; q < 8; ++q) {
                float4 v = *reinterpret_cast<const float4*>(xr + q * 4);
                row[q * 4 + 0] = v.x; row[q * 4 + 1] = v.y;
                row[q * 4 + 2] = v.z; row[q * 4 + 3] = v.w;
            }
            float w0 = wr[ic * 25 + ky * 5 + 0];
            float w1 = wr[ic * 25 + ky * 5 + 1];
            float w2 = wr[ic * 25 + ky * 5 + 2];
            float w3 = wr[ic * 25 + ky * 5 + 3];
            float w4 = wr[ic * 25 + ky * 5 + 4];
#pragma unroll
            for (int ox = 0; ox < 14; ++ox) {
                float s = acc[ox];
                s = fmaf(row[2 * ox + 0], w0, s);
                s = fmaf(row[2 * ox + 1], w1, s);
                s = fmaf(row[2 * ox + 2], w2, s);
                s = fmaf(row[2 * ox + 3], w3, s);
                s = fmaf(row[2 * ox + 4], w4, s);
                acc[ox] = s;
            }
        }
    }
    float* out = h + ((size_t)(b * AA + oc) * 14 + r) * 14;
#pragma unroll
    for (int q = 0; q < 7; ++q)
        *reinterpret_cast<float2*>(out + q * 2) = make_float2(acc[q * 2], acc[q * 2 + 1]);
}

// ---------------- block reduce helper (s, s2) ----------------
__device__ __forceinline__ void blk_reduce2(float& s, float& s2, int tid) {
#pragma unroll
    for (int o = 32; o > 0; o >>= 1) { s += __shfl_down(s, o); s2 += __shfl_down(s2, o); }
    __shared__ float ls[4], lq[4];
    int lane = tid & 63, wid = tid >> 6;
    if (lane == 0) { ls[wid] = s; lq[wid] = s2; }
    __syncthreads();
    if (tid == 0) {
        s = ls[0] + ls[1] + ls[2] + ls[3];
        s2 = lq[0] + lq[1] + lq[2] + lq[3];
    }
}

// ---------------- bn1 stats stage A: 1024 blocks, partials [2][128][8] ----------------
__global__ void k_bnstats1a(const float* __restrict__ h, float* __restrict__ part) {
    int c = blockIdx.x & 127, sl = blockIdx.x >> 7;
    int tid = threadIdx.x;
    float s = 0.f, s2 = 0.f;
    for (int j = tid; j < 16 * 196; j += 256) {
        int b = sl * 16 + j / 196, hw = j % 196;
        float v = h[((size_t)b * AA + c) * 196 + hw];
        s += v; s2 += v * v;
    }
    blk_reduce2(s, s2, tid);
    if (tid == 0) { part[c * 8 + sl] = s; part[1024 + c * 8 + sl] = s2; }
}

// ---------------- bn1 finalize: 1 block x 128 ----------------
__global__ void k_bnfin1(const float* __restrict__ part, const float* __restrict__ g,
                         const float* __restrict__ be, float* __restrict__ bn1) {
    int c = threadIdx.x;
    float s = 0.f, s2 = 0.f;
#pragma unroll
    for (int sl = 0; sl < 8; ++sl) { s += part[c * 8 + sl]; s2 += part[1024 + c * 8 + sl]; }
    const float n = (float)(NB * 196);
    float mu = s / n;
    float var = s2 / n - mu * mu;
    float sc = g[c] * rsqrtf(var + 1e-5f);
    bn1[c] = sc;
    bn1[AA + c] = be[c] - mu * sc;
}

// ---------------- prep weights: prim_w [544][1152] f32 -> Ah/Al [576][1152] bf16 ------
__global__ void k_prepw(const float* __restrict__ w, unsigned short* __restrict__ Ah,
                        unsigned short* __restrict__ Al) {
    int t = blockIdx.x * 256 + threadIdx.x;
    if (t >= MG * (KG / 8)) return;
    int row = t / (KG / 8), seg = t % (KG / 8);
    alignas(16) unsigned short hi[8], lo[8];
    if (row < CH2) {
        const float* src = w + (size_t)row * KG + seg * 8;
#pragma unroll
        for (int j = 0; j < 8; ++j) {
            float v = src[j];
            unsigned short hh = f2bf(v);
            hi[j] = hh;
            lo[j] = f2bf(v - bf2f(hh));
        }
    } else {
#pragma unroll
        for (int j = 0; j < 8; ++j) { hi[j] = 0; lo[j] = 0; }
    }
    *reinterpret_cast<uint4*>(Ah + (size_t)row * KG + seg * 8) = *reinterpret_cast<const uint4*>(hi);
    *reinterpret_cast<uint4*>(Al + (size_t)row * KG + seg * 8) = *reinterpret_cast<const uint4*>(lo);
}

// ---------------- im2col + fused bn1+relu: h -> Bh/Bl [4608][1152] bf16 ---------------
__global__ void k_im2col(const float* __restrict__ h, const float* __restrict__ bn1,
                         unsigned short* __restrict__ Bh, unsigned short* __restrict__ Bl) {
    int t = blockIdx.x * 256 + threadIdx.x;
    if (t >= NG * (KG / 8)) return;
    int n = t / (KG / 8), seg = t % (KG / 8);
    int b = n / 36, xy = n % 36;
    int oy = xy / 6, ox = xy % 6;
    const float* hb = h + (size_t)b * (AA * 196) + (2 * oy) * 14 + 2 * ox;
    alignas(16) unsigned short hi[8], lo[8];
#pragma unroll
    for (int j = 0; j < 8; ++j) {
        int k = seg * 8 + j;
        int ic = k / 9, kk = k - ic * 9;
        int ky = kk / 3, kx = kk - ky * 3;
        float v = hb[ic * 196 + ky * 14 + kx];
        v = fmaxf(fmaf(v, bn1[ic], bn1[AA + ic]), 0.f);
        unsigned short hh = f2bf(v);
        hi[j] = hh;
        lo[j] = f2bf(v - bf2f(hh));
    }
    *reinterpret_cast<uint4*>(Bh + (size_t)n * KG + seg * 8) = *reinterpret_cast<const uint4*>(hi);
    *reinterpret_cast<uint4*>(Bl + (size_t)n * KG + seg * 8) = *reinterpret_cast<const uint4*>(lo);
}

// ---------------- conv2 as split-bf16 MFMA GEMM, XCD-swizzled 64x64 tiles -------------
__global__ __launch_bounds__(256, 4) void k_gemm(const unsigned short* __restrict__ Ah,
                                                 const unsigned short* __restrict__ Al,
                                                 const unsigned short* __restrict__ Bh,
                                                 const unsigned short* __restrict__ Bl,
                                                 float* __restrict__ pcT) {
    __shared__ alignas(16) unsigned short sAh[64][44], sAl[64][44];
    __shared__ alignas(16) unsigned short sBh[64][44], sBl[64][44];
    const int s = blockIdx.x;
    const int k8 = s & 7, j = s >> 3;
    const int jm = j / 9;
    const int y = k8 + 8 * jm;
    const int xg = j - 9 * jm;
    const int oc0 = xg * 64;
    const int n0 = y * 64;
    const int tid = threadIdx.x;
    const int lane = tid & 63, wv = tid >> 6;
    const int wm = wv >> 1, wn = wv & 1;
    const int quad = lane >> 4, r16 = lane & 15;
    const int srow = tid >> 2, sseg = tid & 3;

    facc4 acc[2][2] = {};
    const size_t gA = (size_t)(oc0 + srow) * KG + sseg * 8;
    const size_t gB = (size_t)(n0 + srow) * KG + sseg * 8;

    for (int ks = 0; ks < KG / 32; ++ks) {
        const int k0 = ks * 32;
        uint4 vAh = *reinterpret_cast<const uint4*>(Ah + gA + k0);
        uint4 vAl = *reinterpret_cast<const uint4*>(Al + gA + k0);
        uint4 vBh = *reinterpret_cast<const uint4*>(Bh + gB + k0);
        uint4 vBl = *reinterpret_cast<const uint4*>(Bl + gB + k0);
        __syncthreads();
        *reinterpret_cast<uint4*>(&sAh[srow][sseg * 8]) = vAh;
        *reinterpret_cast<uint4*>(&sAl[srow][sseg * 8]) = vAl;
        *reinterpret_cast<uint4*>(&sBh[srow][sseg * 8]) = vBh;
        *reinterpret_cast<uint4*>(&sBl[srow][sseg * 8]) = vBl;
        __syncthreads();
        bfrag8 ah[2], al[2], bh[2], bl[2];
#pragma unroll
        for (int i = 0; i < 2; ++i) {
            ah[i] = *reinterpret_cast<const bfrag8*>(&sAh[wm * 32 + i * 16 + r16][quad * 8]);
            al[i] = *reinterpret_cast<const bfrag8*>(&sAl[wm * 32 + i * 16 + r16][quad * 8]);
            bh[i] = *reinterpret_cast<const bfrag8*>(&sBh[wn * 32 + i * 16 + r16][quad * 8]);
            bl[i] = *reinterpret_cast<const bfrag8*>(&sBl[wn * 32 + i * 16 + r16][quad * 8]);
        }
#pragma unroll
        for (int i = 0; i < 2; ++i)
#pragma unroll
            for (int jj = 0; jj < 2; ++jj) {
                acc[i][jj] = __builtin_amdgcn_mfma_f32_16x16x32_bf16(ah[i], bh[jj], acc[i][jj], 0, 0, 0);
                acc[i][jj] = __builtin_amdgcn_mfma_f32_16x16x32_bf16(ah[i], bl[jj], acc[i][jj], 0, 0, 0);
                acc[i][jj] = __builtin_amdgcn_mfma_f32_16x16x32_bf16(al[i], bh[jj], acc[i][jj], 0, 0, 0);
            }
    }
#pragma unroll
    for (int i = 0; i < 2; ++i) {
        int oc_base = oc0 + wm * 32 + i * 16 + quad * 4;
        if (oc_base >= CH2) continue;
#pragma unroll
        for (int jj = 0; jj < 2; ++jj) {
            int n = n0 + wn * 32 + jj * 16 + r16;
            *reinterpret_cast<facc4*>(pcT + (size_t)n * CH2 + oc_base) = acc[i][jj];
        }
    }
}

// ---------------- bn2 stats stage A: 320 blocks ----------------
__global__ void k_bnstats2a(const float* __restrict__ pcT, float* __restrict__ part) {
    int blk = blockIdx.x, tid = threadIdx.x;
    float s = 0.f, s2 = 0.f;
    if (blk < 256) {
        int i = blk >> 3, sl = blk & 7;
        for (int j = tid; j < 576 * 4; j += 256) {
            int row = sl * 576 + (j >> 2), q = j & 3;
            float4 v = *reinterpret_cast<const float4*>(pcT + (size_t)row * CH2 + i * 16 + q * 4);
            s += v.x + v.y + v.z + v.w;
            s2 += v.x * v.x + v.y * v.y + v.z * v.z + v.w * v.w;
        }
        blk_reduce2(s, s2, tid);
        if (tid == 0) { part[blk] = s; part[256 + blk] = s2; }
    } else {
        int t2 = blk - 256;
        int ch = t2 >> 1, sl = t2 & 1;
        for (int j = tid; j < 2304; j += 256) {
            int row = sl * 2304 + j;
            float v = pcT[(size_t)row * CH2 + BB * DD + ch];
            s += v; s2 += v * v;
        }
        blk_reduce2(s, s2, tid);
        if (tid == 0) { part[512 + t2] = s; part[576 + t2] = s2; }
    }
}

// ---------------- bn2 finalize: 1 block x 64 ----------------
__global__ void k_bnfin2(const float* __restrict__ part,
                         const float* __restrict__ bna_g, const float* __restrict__ bna_b,
                         const float* __restrict__ bnp_g, const float* __restrict__ bnp_b,
                         float* __restrict__ bn2) {
    int t = threadIdx.x;
    if (t < 32) {
        float s = 0.f, s2 = 0.f;
#pragma unroll
        for (int sl = 0; sl < 8; ++sl) { s += part[t * 8 + sl]; s2 += part[256 + t * 8 + sl]; }
        const float n = (float)(NB * DD * 36);
        float mu = s / n, var = s2 / n - mu * mu;
        float sc = bnp_g[t] * rsqrtf(var + 1e-5f);
        bn2[t] = sc; bn2[32 + t] = bnp_b[t] - mu * sc;
    } else {
        int ch = t - 32;
        float s = part[512 + ch * 2] + part[512 + ch * 2 + 1];
        float s2 = part[576 + ch * 2] + part[576 + ch * 2 + 1];
        const float n = (float)(NB * 36);
        float mu = s / n, var = s2 / n - mu * mu;
        float sc = bna_g[ch] * rsqrtf(var + 1e-5f);
        bn2[64 + ch] = sc; bn2[96 + ch] = bna_b[ch] - mu * sc;
    }
}

// ---------------- digamma (args always >= 1.0 here) ----------------
__device__ __forceinline__ float digammaf_(float x) {
    float r = 0.f;
    while (x < 6.f) { r -= 1.f / x; x += 1.f; }
    float xi = 1.f / x;
    float xi2 = xi * xi;
    return r + logf(x) - 0.5f * xi -
           xi2 * (0.0833333333f - xi2 * (0.0083333333f - xi2 * 0.0039682540f));
}

// ---------------- merged routing with in-kernel expectations ----------------
// grid 256: block = (b = blk>>1, half = blk&1). 640 threads = 10 waves; wave c owns
// class c. Prologue (!FIRST): 160 threads compute m/G/base for this b from the
// previous pass's partials (S*i) into LDS. Per iter: P-tile (64 n x 16) + a staged
// to LDS once (all 10 waves share), V computed once, lnp exchanged via LDS for the
// cross-c softmax, stats accumulated. Output partials to S*o (ping-pong vs S*i).
template <int FIRST>
__global__ __launch_bounds__(640) void k_routed(
    const float* __restrict__ pcT, const float* __restrict__ bn2,
    const float* __restrict__ Wij,
    const float* __restrict__ S0i, const float* __restrict__ S1i, const float* __restrict__ S2i,
    float* __restrict__ S0o, float* __restrict__ S1o, float* __restrict__ S2o) {
    const int b = blockIdx.x >> 1, half = blockIdx.x & 1;
    const int tid = threadIdx.x;
    const int c = tid >> 6, lane = tid & 63;
    __shared__ float sLnp[CC][66];
    __shared__ float sBn2[128];
    __shared__ __align__(16) float sP[64][20];
    __shared__ float sA[64];
    __shared__ float sM[CC][16], sGq[CC][16], sBase[CC];
    if (tid < 128) sBn2[tid] = bn2[tid];
    if (!FIRST && tid < 160) {
        // expectations for this b (identical math/order to the old k_expect)
        int cc = tid >> 4, d = tid & 15;
        int bc = b * CC + cc;
        float njraw = S0i[bc] + S0i[NB * CC + bc];
        float nj = njraw + 1e-8f;
        float kappa = 1.f + nj;
        float nu = 17.f + nj;
        float s1 = S1i[bc * 16 + d] + S1i[(NB * CC + bc) * 16 + d];
        float s2v = S2i[bc * 16 + d] + S2i[(NB * CC + bc) * 16 + d];
        float xbar = s1 / nj;
        float sig = (s2v - 2.f * xbar * s1 + xbar * xbar * njraw) / nj;
        float Psi = 1.f + nj * sig + (nj / kappa) * xbar * xbar;
        sM[cc][d] = nj * xbar / kappa;
        sGq[cc][d] = 0.5f * nu / Psi;
        float term = digammaf_(0.5f * (nu + 1.f - (float)(d + 1))) - logf(Psi);
#pragma unroll
        for (int o = 8; o > 0; o >>= 1) term += __shfl_down(term, o, 16);
        if (d == 0) {
            float asum = 0.f;
#pragma unroll
            for (int k = 0; k < CC; ++k)
                asum += 1.f + S0i[b * CC + k] + S0i[NB * CC + b * CC + k] + 1e-8f;
            float elnlam = 16.f * 0.69314718056f + term;
            float elnpi = digammaf_(1.f + nj) - digammaf_(asum);
            float lb = elnpi + 0.5f * elnlam;
            sBase[cc] = lb - 8.f * 1.83787706641f - 8.f / kappa;
        }
    }
    __syncthreads();
    float mc[16], Gc[16], basec = 0.f;
    if (!FIRST) {
#pragma unroll
        for (int d = 0; d < 16; ++d) { mc[d] = sM[c][d]; Gc[d] = sGq[c][d]; }
        basec = sBase[c];
    }
    float s0 = 0.f, s1[16], s2[16];
#pragma unroll
    for (int d = 0; d < 16; ++d) { s1[d] = 0.f; s2[d] = 0.f; }

#pragma unroll 1
    for (int it = 0; it < 9; ++it) {
        // stage P-tile (+bn2) and a for the 64 rows of this iter
        if (tid < 256) {
            int r = tid >> 2, q = tid & 3;
            int n = half * 576 + it * 64 + r;
            int i = n / 36, xy = n - i * 36;
            int row = b * 36 + xy;
            float4 v = *reinterpret_cast<const float4*>(pcT + (size_t)row * CH2 + i * 16 + q * 4);
            float psc = sBn2[i], psh = sBn2[32 + i];
            v.x = fmaf(v.x, psc, psh); v.y = fmaf(v.y, psc, psh);
            v.z = fmaf(v.z, psc, psh); v.w = fmaf(v.w, psc, psh);
            *reinterpret_cast<float4*>(&sP[r][q * 4]) = v;
        } else if (tid < 320) {
            int r = tid - 256;
            int n = half * 576 + it * 64 + r;
            int i = n / 36, xy = n - i * 36;
            int row = b * 36 + xy;
            float va = fmaf(pcT[(size_t)row * CH2 + BB * DD + i], sBn2[64 + i], sBn2[96 + i]);
            sA[r] = 1.f / (1.f + expf(-va));
        }
        __syncthreads();   // A: sP/sA ready
        const int n = half * 576 + it * 64 + lane;
        const int i = n / 36, xy = n - i * 36;
        const float4* wp = reinterpret_cast<const float4*>(Wij + (((size_t)i * CC + c) * 36 + xy) * 16);
        alignas(16) float P[16], W[16];
        *reinterpret_cast<float4*>(&P[0])  = *reinterpret_cast<const float4*>(&sP[lane][0]);
        *reinterpret_cast<float4*>(&P[4])  = *reinterpret_cast<const float4*>(&sP[lane][4]);
        *reinterpret_cast<float4*>(&P[8])  = *reinterpret_cast<const float4*>(&sP[lane][8]);
        *reinterpret_cast<float4*>(&P[12]) = *reinterpret_cast<const float4*>(&sP[lane][12]);
        *reinterpret_cast<float4*>(&W[0])  = wp[0];
        *reinterpret_cast<float4*>(&W[4])  = wp[1];
        *reinterpret_cast<float4*>(&W[8])  = wp[2];
        *reinterpret_cast<float4*>(&W[12]) = wp[3];
        float V[16];
#pragma unroll
        for (int p = 0; p < 4; ++p)
#pragma unroll
            for (int r = 0; r < 4; ++r)
                V[p * 4 + r] = W[p * 4 + 0] * P[0 + r] + W[p * 4 + 1] * P[4 + r] +
                               W[p * 4 + 2] * P[8 + r] + W[p * 4 + 3] * P[12 + r];
        float av = sA[lane];
        float wgt;
        if (FIRST) {
            wgt = 0.1f * av;
            __syncthreads();   // B: all reads of sP/sA done before next stage
        } else {
            float q = 0.f;
#pragma unroll
            for (int d = 0; d < 16; ++d) {
                float dm = V[d] - mc[d];
                q = fmaf(dm * dm, Gc[d], q);
            }
            float lnp = basec - q;
            sLnp[c][lane] = lnp;
            __syncthreads();   // B: sLnp ready; sP/sA reads done
            float mx = -1e30f;
#pragma unroll
            for (int cc = 0; cc < CC; ++cc) mx = fmaxf(mx, sLnp[cc][lane]);
            float ssum = 0.f;
#pragma unroll
            for (int cc = 0; cc < CC; ++cc) ssum += expf(sLnp[cc][lane] - mx);
            wgt = expf(lnp - mx) / ssum * av;
        }
        s0 += wgt;
#pragma unroll
        for (int d = 0; d < 16; ++d) {
            float wv = wgt * V[d];
            s1[d] += wv;
            s2[d] = fmaf(wv, V[d], s2[d]);
        }
    }
    // wave-level reduce of 33 values
#pragma unroll
    for (int o = 32; o > 0; o >>= 1) {
        s0 += __shfl_down(s0, o);
#pragma unroll
        for (int k = 0; k < 16; ++k) {
            s1[k] += __shfl_down(s1[k], o);
            s2[k] += __shfl_down(s2[k], o);
        }
    }
    if (lane == 0) {
        int idx = half * (NB * CC) + b * CC + c;
        S0o[idx] = s0;
#pragma unroll
        for (int k = 0; k < 16; ++k) { S1o[idx * 16 + k] = s1[k]; S2o[idx * 16 + k] = s2[k]; }
    }
}

// ---------------- final expectations (logits) from partials ----------------
__global__ void k_expect_final(const float* __restrict__ S0p, const float* __restrict__ S1p,
                               const float* __restrict__ S2p, float* __restrict__ logits) {
    int b = blockIdx.x;
    int c = threadIdx.x;
    __shared__ float alph[CC];
    float njraw = 0.f;
    if (c < CC) {
        njraw = S0p[b * CC + c] + S0p[NB * CC + b * CC + c];
        alph[c] = 1.f + njraw + 1e-8f;
    }
    __syncthreads();
    if (c < CC) {
        int bc = b * CC + c;
        float nj = njraw + 1e-8f;
        float asum = 0.f;
#pragma unroll
        for (int k = 0; k < CC; ++k) asum += alph[k];
        float kappa = 1.f + nj;
        float nu = 17.f + nj;
        float S0 = njraw;
        float elnlam = 16.f * 0.69314718056f;
        for (int d = 0; d < 16; ++d) {
            float s1 = S1p[bc * 16 + d] + S1p[(NB * CC + bc) * 16 + d];
            float s2v = S2p[bc * 16 + d] + S2p[(NB * CC + bc) * 16 + d];
            float xbar = s1 / nj;
            float sig = (s2v - 2.f * xbar * s1 + xbar * xbar * S0) / nj;
            float Psi = 1.f + nj * sig + (nj / kappa) * xbar * xbar;
            elnlam += digammaf_(0.5f * (nu + 1.f - (float)(d + 1))) - logf(Psi);
        }
        float elnpi = digammaf_(1.f + nj) - digammaf_(asum);
        logits[bc] = elnpi + 0.5f * elnlam;
    }
}

// ---------------- final: BN over batch per class + sigmoid ----------------
__global__ void k_final(const float* __restrict__ logits, float* __restrict__ out) {
    int c = blockIdx.x;
    int b = threadIdx.x;
    float v = logits[b * CC + c];
    float s = v, s2 = v * v;
#pragma unroll
    for (int o = 32; o > 0; o >>= 1) { s += __shfl_down(s, o); s2 += __shfl_down(s2, o); }
    __shared__ float ls[2], lq[2];
    int lane = b & 63, wid = b >> 6;
    if (lane == 0) { ls[wid] = s; lq[wid] = s2; }
    __syncthreads();
    float mu = (ls[0] + ls[1]) * (1.f / 128.f);
    float var = (lq[0] + lq[1]) * (1.f / 128.f) - mu * mu;
    out[b * CC + c] = 1.f / (1.f + expf(-(v - mu) * rsqrtf(var + 1e-5f)));
}

extern "C" void kernel_launch(void* const* d_in, const int* in_sizes, int n_in,
                              void* d_out, int out_size, void* d_ws, size_t ws_size,
                              hipStream_t stream) {
    (void)in_sizes; (void)n_in; (void)out_size; (void)ws_size;
    const float* x       = (const float*)d_in[0];
    const float* conv1_w = (const float*)d_in[1];
    const float* bn1_g   = (const float*)d_in[2];
    const float* bn1_b   = (const float*)d_in[3];
    const float* prim_w  = (const float*)d_in[4];
    const float* bna_g   = (const float*)d_in[5];
    const float* bna_b   = (const float*)d_in[6];
    const float* bnp_g   = (const float*)d_in[7];
    const float* bnp_b   = (const float*)d_in[8];
    const float* Wij     = (const float*)d_in[9];

    float* ws = (float*)d_ws;
    float* h   = ws;                                          // 3,211,264 f32
    float* pcT = ws + 3211264;                                // 2,506,752 f32 [4608][544]
    unsigned short* Bh = (unsigned short*)(ws + 5718016);     // 5,308,416 bf16
    unsigned short* Bl = (unsigned short*)(ws + 8372224);     // 5,308,416 bf16
    unsigned short* Ahp = (unsigned short*)(ws + 11026432);   //   663,552 bf16
    unsigned short* Alp = (unsigned short*)(ws + 11358208);   //   663,552 bf16
    float* bn1    = ws + 11689984;   // 256
    float* bn2    = ws + 11690240;   // 128
    float* S0a    = ws + 11690368;   // 2,560
    float* S1a    = ws + 11692928;   // 40,960
    float* S2a    = ws + 11733888;   // 40,960
    float* S0b    = ws + 11774848;   // 2,560
    float* S1b    = ws + 11777408;   // 40,960
    float* S2b    = ws + 11818368;   // 40,960
    float* logits = ws + 11859328;   // 1,280
    float* part1  = ws + 11860608;   // 2,048
    float* part2  = ws + 11862656;   //   640
    float* out    = (float*)d_out;

    k_conv1<<<dim3(7, 128), 256, 0, stream>>>(x, conv1_w, h);
    k_bnstats1a<<<1024, 256, 0, stream>>>(h, part1);
    k_bnfin1<<<1, 128, 0, stream>>>(part1, bn1_g, bn1_b, bn1);
    k_prepw<<<324, 256, 0, stream>>>(prim_w, Ahp, Alp);
    k_im2col<<<2592, 256, 0, stream>>>(h, bn1, Bh, Bl);
    k_gemm<<<648, 256, 0, stream>>>(Ahp, Alp, Bh, Bl, pcT);
    k_bnstats2a<<<320, 256, 0, stream>>>(pcT, part2);
    k_bnfin2<<<1, 64, 0, stream>>>(part2, bna_g, bna_b, bnp_g, bnp_b, bn2);

    // routing: iter0 (R = 1/C) -> A; iter1 (expect from A) -> B; iter2 (expect from B) -> A
    k_routed<1><<<256, 640, 0, stream>>>(pcT, bn2, Wij, S0a, S1a, S2a, S0a, S1a, S2a);
    k_routed<0><<<256, 640, 0, stream>>>(pcT, bn2, Wij, S0a, S1a, S2a, S0b, S1b, S2b);
    k_routed<0><<<256, 640, 0, stream>>>(pcT, bn2, Wij, S0b, S1b, S2b, S0a, S1a, S2a);
    k_expect_final<<<128, 64, 0, stream>>>(S0a, S1a, S2a, logits);

    k_final<<<10, 128, 0, stream>>>(logits, out);
}

// Round 15
// 178.236 us; speedup vs baseline: 1.7573x; 1.0548x over previous
//
#include <hip/hip_runtime.h>
#include <hip/hip_bf16.h>

// Problem constants
#define NB 128     // batch
#define AA 128     // conv1 out channels
#define BB 32      // capsule types
#define CC 10      // classes
#define KK 6       // primary grid
#define DD 16      // pose dim
#define NN 1152    // B*K*K
#define H1 14      // conv1 out spatial
#define CH2 544    // B*D+B
#define NG 4608    // GEMM N = NB*36
#define KG 1152    // GEMM K = 128*9
#define MG 576     // GEMM M padded (544 -> 9*64)

typedef short bfrag8 __attribute__((ext_vector_type(8)));   // 8 bf16 (4 VGPRs)
typedef float facc4 __attribute__((ext_vector_type(4)));    // 4 fp32 acc

__device__ __forceinline__ unsigned short f2bf(float f) {   // RNE f32->bf16
    unsigned u = __float_as_uint(f);
    u += 0x7FFF + ((u >> 16) & 1);
    return (unsigned short)(u >> 16);
}
__device__ __forceinline__ float bf2f(unsigned short s) {
    return __uint_as_float(((unsigned)s) << 16);
}

// ---------------- conv1 (LDS-staged): (128,3,32,32) -> (128,128,14,14), 5x5 s2 --------
__global__ __launch_bounds__(256, 3) void k_conv1(const float* __restrict__ x,
                                                  const float* __restrict__ w,
                                                  float* __restrict__ h) {
    __shared__ __align__(16) float sX[3][7][32];   //  2,688 B
    __shared__ float sWf[AA * 75];                 // 38,400 B
    const int p = blockIdx.x;
    const int b = blockIdx.y;
    const int tid = threadIdx.x;
    for (int j = tid; j < AA * 75; j += 256) sWf[j] = w[j];
    for (int j = tid; j < 3 * 7 * 32; j += 256) {
        int col = j & 31; int t2 = j >> 5; int row = t2 % 7; int ic = t2 / 7;
        sX[ic][row][col] = x[b * 3072 + ic * 1024 + (4 * p + row) * 32 + col];
    }
    __syncthreads();
    const int oc = tid & 127, ry = tid >> 7;
    const int r = 2 * p + ry;
    float acc[14];
#pragma unroll
    for (int j = 0; j < 14; ++j) acc[j] = 0.f;
    const float* wr = sWf + oc * 75;
#pragma unroll
    for (int ic = 0; ic < 3; ++ic) {
#pragma unroll
        for (int ky = 0; ky < 5; ++ky) {
            const float* xr = &sX[ic][2 * ry + ky][0];
            float row[32];
#pragma unroll
            for (int q = 0; q < 8; ++q) {
                float4 v = *reinterpret_cast<const float4*>(xr + q * 4);
                row[q * 4 + 0] = v.x; row[q * 4 + 1] = v.y;
                row[q * 4 + 2] = v.z; row[q * 4 + 3] = v.w;
            }
            float w0 = wr[ic * 25 + ky * 5 + 0];
            float w1 = wr[ic * 25 + ky * 5 + 1];
            float w2 = wr[ic * 25 + ky * 5 + 2];
            float w3 = wr[ic * 25 + ky * 5 + 3];
            float w4 = wr[ic * 25 + ky * 5 + 4];
#pragma unroll
            for (int ox = 0; ox < 14; ++ox) {
                float s = acc[ox];
                s = fmaf(row[2 * ox + 0], w0, s);
                s = fmaf(row[2 * ox + 1], w1, s);
                s = fmaf(row[2 * ox + 2], w2, s);
                s = fmaf(row[2 * ox + 3], w3, s);
                s = fmaf(row[2 * ox + 4], w4, s);
                acc[ox] = s;
            }
        }
    }
    float* out = h + ((size_t)(b * AA + oc) * 14 + r) * 14;
#pragma unroll
    for (int q = 0; q < 7; ++q)
        *reinterpret_cast<float2*>(out + q * 2) = make_float2(acc[q * 2], acc[q * 2 + 1]);
}

// ---------------- block reduce helper (s, s2) ----------------
__device__ __forceinline__ void blk_reduce2(float& s, float& s2, int tid) {
#pragma unroll
    for (int o = 32; o > 0; o >>= 1) { s += __shfl_down(s, o); s2 += __shfl_down(s2, o); }
    __shared__ float ls[4], lq[4];
    int lane = tid & 63, wid = tid >> 6;
    if (lane == 0) { ls[wid] = s; lq[wid] = s2; }
    __syncthreads();
    if (tid == 0) {
        s = ls[0] + ls[1] + ls[2] + ls[3];
        s2 = lq[0] + lq[1] + lq[2] + lq[3];
    }
}

// ---------------- bn1 stats stage A: 1024 blocks, partials [2][128][8] ----------------
__global__ void k_bnstats1a(const float* __restrict__ h, float* __restrict__ part) {
    int c = blockIdx.x & 127, sl = blockIdx.x >> 7;
    int tid = threadIdx.x;
    float s = 0.f, s2 = 0.f;
    for (int j = tid; j < 16 * 196; j += 256) {
        int b = sl * 16 + j / 196, hw = j % 196;
        float v = h[((size_t)b * AA + c) * 196 + hw];
        s += v; s2 += v * v;
    }
    blk_reduce2(s, s2, tid);
    if (tid == 0) { part[c * 8 + sl] = s; part[1024 + c * 8 + sl] = s2; }
}

// ---------------- merged prepw + im2col (bn1 finalized in-block) ----------------
// blocks [0,324): weights -> Ah/Al split planes.
// blocks [324,2916): im2col of h with bn1+relu fused -> Bh/Bl. Each block first
// computes the bn1 coefficients from part1 (identical order to old k_bnfin1).
__global__ void k_pim(const float* __restrict__ w, const float* __restrict__ h,
                      const float* __restrict__ part1,
                      const float* __restrict__ bn1_g, const float* __restrict__ bn1_b,
                      unsigned short* __restrict__ Ah, unsigned short* __restrict__ Al,
                      unsigned short* __restrict__ Bh, unsigned short* __restrict__ Bl) {
    const int blk = blockIdx.x;
    const int tid = threadIdx.x;
    if (blk < 324) {
        int t = blk * 256 + tid;                  // exactly MG*144 items
        int row = t / (KG / 8), seg = t % (KG / 8);
        alignas(16) unsigned short hi[8], lo[8];
        if (row < CH2) {
            const float* src = w + (size_t)row * KG + seg * 8;
#pragma unroll
            for (int j = 0; j < 8; ++j) {
                float v = src[j];
                unsigned short hh = f2bf(v);
                hi[j] = hh;
                lo[j] = f2bf(v - bf2f(hh));
            }
        } else {
#pragma unroll
            for (int j = 0; j < 8; ++j) { hi[j] = 0; lo[j] = 0; }
        }
        *reinterpret_cast<uint4*>(Ah + (size_t)row * KG + seg * 8) = *reinterpret_cast<const uint4*>(hi);
        *reinterpret_cast<uint4*>(Al + (size_t)row * KG + seg * 8) = *reinterpret_cast<const uint4*>(lo);
        return;
    }
    __shared__ float sBn1[2 * AA];
    if (tid < AA) {
        int c = tid;
        float s = 0.f, s2 = 0.f;
#pragma unroll
        for (int sl = 0; sl < 8; ++sl) { s += part1[c * 8 + sl]; s2 += part1[1024 + c * 8 + sl]; }
        const float n = (float)(NB * 196);
        float mu = s / n;
        float var = s2 / n - mu * mu;
        float sc = bn1_g[c] * rsqrtf(var + 1e-5f);
        sBn1[c] = sc;
        sBn1[AA + c] = bn1_b[c] - mu * sc;
    }
    __syncthreads();
    int t = (blk - 324) * 256 + tid;              // exactly NG*144 items
    int n = t / (KG / 8), seg = t % (KG / 8);
    int b = n / 36, xy = n % 36;
    int oy = xy / 6, ox = xy % 6;
    const float* hb = h + (size_t)b * (AA * 196) + (2 * oy) * 14 + 2 * ox;
    alignas(16) unsigned short hi[8], lo[8];
#pragma unroll
    for (int j = 0; j < 8; ++j) {
        int k = seg * 8 + j;
        int ic = k / 9, kk = k - ic * 9;
        int ky = kk / 3, kx = kk - ky * 3;
        float v = hb[ic * 196 + ky * 14 + kx];
        v = fmaxf(fmaf(v, sBn1[ic], sBn1[AA + ic]), 0.f);
        unsigned short hh = f2bf(v);
        hi[j] = hh;
        lo[j] = f2bf(v - bf2f(hh));
    }
    *reinterpret_cast<uint4*>(Bh + (size_t)n * KG + seg * 8) = *reinterpret_cast<const uint4*>(hi);
    *reinterpret_cast<uint4*>(Bl + (size_t)n * KG + seg * 8) = *reinterpret_cast<const uint4*>(lo);
}

// ---------------- conv2 as split-bf16 MFMA GEMM, XCD-swizzled, pipelined --------------
// Prologue loads tile 0; in-loop, loads for ks+1 issue BEFORE compute(ks) so the
// global latency hides under the 12 MFMAs.
__global__ __launch_bounds__(256, 4) void k_gemm(const unsigned short* __restrict__ Ah,
                                                 const unsigned short* __restrict__ Al,
                                                 const unsigned short* __restrict__ Bh,
                                                 const unsigned short* __restrict__ Bl,
                                                 float* __restrict__ pcT) {
    __shared__ alignas(16) unsigned short sAh[64][44], sAl[64][44];
    __shared__ alignas(16) unsigned short sBh[64][44], sBl[64][44];
    const int s = blockIdx.x;
    const int k8 = s & 7, j = s >> 3;
    const int jm = j / 9;
    const int y = k8 + 8 * jm;
    const int xg = j - 9 * jm;
    const int oc0 = xg * 64;
    const int n0 = y * 64;
    const int tid = threadIdx.x;
    const int lane = tid & 63, wv = tid >> 6;
    const int wm = wv >> 1, wn = wv & 1;
    const int quad = lane >> 4, r16 = lane & 15;
    const int srow = tid >> 2, sseg = tid & 3;

    facc4 acc[2][2] = {};
    const size_t gA = (size_t)(oc0 + srow) * KG + sseg * 8;
    const size_t gB = (size_t)(n0 + srow) * KG + sseg * 8;

    // LOAD(0)
    uint4 vAh = *reinterpret_cast<const uint4*>(Ah + gA);
    uint4 vAl = *reinterpret_cast<const uint4*>(Al + gA);
    uint4 vBh = *reinterpret_cast<const uint4*>(Bh + gB);
    uint4 vBl = *reinterpret_cast<const uint4*>(Bl + gB);

    for (int ks = 0; ks < KG / 32; ++ks) {
        __syncthreads();   // previous compute done reading LDS
        *reinterpret_cast<uint4*>(&sAh[srow][sseg * 8]) = vAh;
        *reinterpret_cast<uint4*>(&sAl[srow][sseg * 8]) = vAl;
        *reinterpret_cast<uint4*>(&sBh[srow][sseg * 8]) = vBh;
        *reinterpret_cast<uint4*>(&sBl[srow][sseg * 8]) = vBl;
        __syncthreads();
        // LOAD(ks+1): lands during compute
        if (ks + 1 < KG / 32) {
            const int k0n = (ks + 1) * 32;
            vAh = *reinterpret_cast<const uint4*>(Ah + gA + k0n);
            vAl = *reinterpret_cast<const uint4*>(Al + gA + k0n);
            vBh = *reinterpret_cast<const uint4*>(Bh + gB + k0n);
            vBl = *reinterpret_cast<const uint4*>(Bl + gB + k0n);
        }
        // COMPUTE(ks)
        bfrag8 ah[2], al[2], bh[2], bl[2];
#pragma unroll
        for (int i = 0; i < 2; ++i) {
            ah[i] = *reinterpret_cast<const bfrag8*>(&sAh[wm * 32 + i * 16 + r16][quad * 8]);
            al[i] = *reinterpret_cast<const bfrag8*>(&sAl[wm * 32 + i * 16 + r16][quad * 8]);
            bh[i] = *reinterpret_cast<const bfrag8*>(&sBh[wn * 32 + i * 16 + r16][quad * 8]);
            bl[i] = *reinterpret_cast<const bfrag8*>(&sBl[wn * 32 + i * 16 + r16][quad * 8]);
        }
#pragma unroll
        for (int i = 0; i < 2; ++i)
#pragma unroll
            for (int jj = 0; jj < 2; ++jj) {
                acc[i][jj] = __builtin_amdgcn_mfma_f32_16x16x32_bf16(ah[i], bh[jj], acc[i][jj], 0, 0, 0);
                acc[i][jj] = __builtin_amdgcn_mfma_f32_16x16x32_bf16(ah[i], bl[jj], acc[i][jj], 0, 0, 0);
                acc[i][jj] = __builtin_amdgcn_mfma_f32_16x16x32_bf16(al[i], bh[jj], acc[i][jj], 0, 0, 0);
            }
    }
#pragma unroll
    for (int i = 0; i < 2; ++i) {
        int oc_base = oc0 + wm * 32 + i * 16 + quad * 4;
        if (oc_base >= CH2) continue;
#pragma unroll
        for (int jj = 0; jj < 2; ++jj) {
            int n = n0 + wn * 32 + jj * 16 + r16;
            *reinterpret_cast<facc4*>(pcT + (size_t)n * CH2 + oc_base) = acc[i][jj];
        }
    }
}

// ---------------- bn2 stats stage A: 320 blocks ----------------
__global__ void k_bnstats2a(const float* __restrict__ pcT, float* __restrict__ part) {
    int blk = blockIdx.x, tid = threadIdx.x;
    float s = 0.f, s2 = 0.f;
    if (blk < 256) {
        int i = blk >> 3, sl = blk & 7;
        for (int j = tid; j < 576 * 4; j += 256) {
            int row = sl * 576 + (j >> 2), q = j & 3;
            float4 v = *reinterpret_cast<const float4*>(pcT + (size_t)row * CH2 + i * 16 + q * 4);
            s += v.x + v.y + v.z + v.w;
            s2 += v.x * v.x + v.y * v.y + v.z * v.z + v.w * v.w;
        }
        blk_reduce2(s, s2, tid);
        if (tid == 0) { part[blk] = s; part[256 + blk] = s2; }
    } else {
        int t2 = blk - 256;
        int ch = t2 >> 1, sl = t2 & 1;
        for (int j = tid; j < 2304; j += 256) {
            int row = sl * 2304 + j;
            float v = pcT[(size_t)row * CH2 + BB * DD + ch];
            s += v; s2 += v * v;
        }
        blk_reduce2(s, s2, tid);
        if (tid == 0) { part[512 + t2] = s; part[576 + t2] = s2; }
    }
}

// ---------------- digamma (args always >= 1.0 here) ----------------
__device__ __forceinline__ float digammaf_(float x) {
    float r = 0.f;
    while (x < 6.f) { r -= 1.f / x; x += 1.f; }
    float xi = 1.f / x;
    float xi2 = xi * xi;
    return r + logf(x) - 0.5f * xi -
           xi2 * (0.0833333333f - xi2 * (0.0083333333f - xi2 * 0.0039682540f));
}

// ---------------- merged routing: bn2 finalize + expectations + update + stats --------
// grid 256: block = (b = blk>>1, half = blk&1). 640 threads = 10 waves; wave c owns
// class c. Prologue: threads <64 finalize bn2 from part2 (identical order to old
// k_bnfin2); for !FIRST threads <160 compute m/G/base from the previous partials.
// Per iter: P-tile + a staged to LDS once (shared by all 10 waves), V computed once,
// lnp exchanged via LDS for the cross-c softmax, stats accumulated in registers.
template <int FIRST>
__global__ __launch_bounds__(640) void k_routed(
    const float* __restrict__ pcT, const float* __restrict__ part2,
    const float* __restrict__ bna_g, const float* __restrict__ bna_b,
    const float* __restrict__ bnp_g, const float* __restrict__ bnp_b,
    const float* __restrict__ Wij,
    const float* __restrict__ S0i, const float* __restrict__ S1i, const float* __restrict__ S2i,
    float* __restrict__ S0o, float* __restrict__ S1o, float* __restrict__ S2o) {
    const int b = blockIdx.x >> 1, half = blockIdx.x & 1;
    const int tid = threadIdx.x;
    const int c = tid >> 6, lane = tid & 63;
    __shared__ float sLnp[CC][66];
    __shared__ float sBn2[128];
    __shared__ __align__(16) float sP[64][20];
    __shared__ float sA[64];
    __shared__ float sM[CC][16], sGq[CC][16], sBase[CC];
    if (tid < 64) {
        if (tid < 32) {
            float s = 0.f, s2 = 0.f;
#pragma unroll
            for (int sl = 0; sl < 8; ++sl) { s += part2[tid * 8 + sl]; s2 += part2[256 + tid * 8 + sl]; }
            const float n = (float)(NB * DD * 36);
            float mu = s / n, var = s2 / n - mu * mu;
            float sc = bnp_g[tid] * rsqrtf(var + 1e-5f);
            sBn2[tid] = sc; sBn2[32 + tid] = bnp_b[tid] - mu * sc;
        } else {
            int ch = tid - 32;
            float s = part2[512 + ch * 2] + part2[512 + ch * 2 + 1];
            float s2 = part2[576 + ch * 2] + part2[576 + ch * 2 + 1];
            const float n = (float)(NB * 36);
            float mu = s / n, var = s2 / n - mu * mu;
            float sc = bna_g[ch] * rsqrtf(var + 1e-5f);
            sBn2[64 + ch] = sc; sBn2[96 + ch] = bna_b[ch] - mu * sc;
        }
    }
    if (!FIRST && tid < 160) {
        // expectations for this b (identical math/order to the old k_expect)
        int cc = tid >> 4, d = tid & 15;
        int bc = b * CC + cc;
        float njraw = S0i[bc] + S0i[NB * CC + bc];
        float nj = njraw + 1e-8f;
        float kappa = 1.f + nj;
        float nu = 17.f + nj;
        float s1 = S1i[bc * 16 + d] + S1i[(NB * CC + bc) * 16 + d];
        float s2v = S2i[bc * 16 + d] + S2i[(NB * CC + bc) * 16 + d];
        float xbar = s1 / nj;
        float sig = (s2v - 2.f * xbar * s1 + xbar * xbar * njraw) / nj;
        float Psi = 1.f + nj * sig + (nj / kappa) * xbar * xbar;
        sM[cc][d] = nj * xbar / kappa;
        sGq[cc][d] = 0.5f * nu / Psi;
        float term = digammaf_(0.5f * (nu + 1.f - (float)(d + 1))) - logf(Psi);
#pragma unroll
        for (int o = 8; o > 0; o >>= 1) term += __shfl_down(term, o, 16);
        if (d == 0) {
            float asum = 0.f;
#pragma unroll
            for (int k = 0; k < CC; ++k)
                asum += 1.f + S0i[b * CC + k] + S0i[NB * CC + b * CC + k] + 1e-8f;
            float elnlam = 16.f * 0.69314718056f + term;
            float elnpi = digammaf_(1.f + nj) - digammaf_(asum);
            float lb = elnpi + 0.5f * elnlam;
            sBase[cc] = lb - 8.f * 1.83787706641f - 8.f / kappa;
        }
    }
    __syncthreads();
    float mc[16], Gc[16], basec = 0.f;
    if (!FIRST) {
#pragma unroll
        for (int d = 0; d < 16; ++d) { mc[d] = sM[c][d]; Gc[d] = sGq[c][d]; }
        basec = sBase[c];
    }
    float s0 = 0.f, s1[16], s2[16];
#pragma unroll
    for (int d = 0; d < 16; ++d) { s1[d] = 0.f; s2[d] = 0.f; }

#pragma unroll 1
    for (int it = 0; it < 9; ++it) {
        // stage P-tile (+bn2) and a for the 64 rows of this iter
        if (tid < 256) {
            int r = tid >> 2, q = tid & 3;
            int n = half * 576 + it * 64 + r;
            int i = n / 36, xy = n - i * 36;
            int row = b * 36 + xy;
            float4 v = *reinterpret_cast<const float4*>(pcT + (size_t)row * CH2 + i * 16 + q * 4);
            float psc = sBn2[i], psh = sBn2[32 + i];
            v.x = fmaf(v.x, psc, psh); v.y = fmaf(v.y, psc, psh);
            v.z = fmaf(v.z, psc, psh); v.w = fmaf(v.w, psc, psh);
            *reinterpret_cast<float4*>(&sP[r][q * 4]) = v;
        } else if (tid < 320) {
            int r = tid - 256;
            int n = half * 576 + it * 64 + r;
            int i = n / 36, xy = n - i * 36;
            int row = b * 36 + xy;
            float va = fmaf(pcT[(size_t)row * CH2 + BB * DD + i], sBn2[64 + i], sBn2[96 + i]);
            sA[r] = 1.f / (1.f + expf(-va));
        }
        __syncthreads();   // A: sP/sA ready
        const int n = half * 576 + it * 64 + lane;
        const int i = n / 36, xy = n - i * 36;
        const float4* wp = reinterpret_cast<const float4*>(Wij + (((size_t)i * CC + c) * 36 + xy) * 16);
        alignas(16) float P[16], W[16];
        *reinterpret_cast<float4*>(&P[0])  = *reinterpret_cast<const float4*>(&sP[lane][0]);
        *reinterpret_cast<float4*>(&P[4])  = *reinterpret_cast<const float4*>(&sP[lane][4]);
        *reinterpret_cast<float4*>(&P[8])  = *reinterpret_cast<const float4*>(&sP[lane][8]);
        *reinterpret_cast<float4*>(&P[12]) = *reinterpret_cast<const float4*>(&sP[lane][12]);
        *reinterpret_cast<float4*>(&W[0])  = wp[0];
        *reinterpret_cast<float4*>(&W[4])  = wp[1];
        *reinterpret_cast<float4*>(&W[8])  = wp[2];
        *reinterpret_cast<float4*>(&W[12]) = wp[3];
        float V[16];
#pragma unroll
        for (int p = 0; p < 4; ++p)
#pragma unroll
            for (int r = 0; r < 4; ++r)
                V[p * 4 + r] = W[p * 4 + 0] * P[0 + r] + W[p * 4 + 1] * P[4 + r] +
                               W[p * 4 + 2] * P[8 + r] + W[p * 4 + 3] * P[12 + r];
        float av = sA[lane];
        float wgt;
        if (FIRST) {
            wgt = 0.1f * av;
            __syncthreads();   // B: all reads of sP/sA done before next stage
        } else {
            float q = 0.f;
#pragma unroll
            for (int d = 0; d < 16; ++d) {
                float dm = V[d] - mc[d];
                q = fmaf(dm * dm, Gc[d], q);
            }
            float lnp = basec - q;
            sLnp[c][lane] = lnp;
            __syncthreads();   // B: sLnp ready; sP/sA reads done
            float mx = -1e30f;
#pragma unroll
            for (int cc = 0; cc < CC; ++cc) mx = fmaxf(mx, sLnp[cc][lane]);
            float ssum = 0.f;
#pragma unroll
            for (int cc = 0; cc < CC; ++cc) ssum += expf(sLnp[cc][lane] - mx);
            wgt = expf(lnp - mx) / ssum * av;
        }
        s0 += wgt;
#pragma unroll
        for (int d = 0; d < 16; ++d) {
            float wv = wgt * V[d];
            s1[d] += wv;
            s2[d] = fmaf(wv, V[d], s2[d]);
        }
    }
    // wave-level reduce of 33 values
#pragma unroll
    for (int o = 32; o > 0; o >>= 1) {
        s0 += __shfl_down(s0, o);
#pragma unroll
        for (int k = 0; k < 16; ++k) {
            s1[k] += __shfl_down(s1[k], o);
            s2[k] += __shfl_down(s2[k], o);
        }
    }
    if (lane == 0) {
        int idx = half * (NB * CC) + b * CC + c;
        S0o[idx] = s0;
#pragma unroll
        for (int k = 0; k < 16; ++k) { S1o[idx * 16 + k] = s1[k]; S2o[idx * 16 + k] = s2[k]; }
    }
}

// ---------------- final expectations (logits) from partials ----------------
__global__ void k_expect_final(const float* __restrict__ S0p, const float* __restrict__ S1p,
                               const float* __restrict__ S2p, float* __restrict__ logits) {
    int b = blockIdx.x;
    int c = threadIdx.x;
    __shared__ float alph[CC];
    float njraw = 0.f;
    if (c < CC) {
        njraw = S0p[b * CC + c] + S0p[NB * CC + b * CC + c];
        alph[c] = 1.f + njraw + 1e-8f;
    }
    __syncthreads();
    if (c < CC) {
        int bc = b * CC + c;
        float nj = njraw + 1e-8f;
        float asum = 0.f;
#pragma unroll
        for (int k = 0; k < CC; ++k) asum += alph[k];
        float kappa = 1.f + nj;
        float nu = 17.f + nj;
        float S0 = njraw;
        float elnlam = 16.f * 0.69314718056f;
        for (int d = 0; d < 16; ++d) {
            float s1 = S1p[bc * 16 + d] + S1p[(NB * CC + bc) * 16 + d];
            float s2v = S2p[bc * 16 + d] + S2p[(NB * CC + bc) * 16 + d];
            float xbar = s1 / nj;
            float sig = (s2v - 2.f * xbar * s1 + xbar * xbar * S0) / nj;
            float Psi = 1.f + nj * sig + (nj / kappa) * xbar * xbar;
            elnlam += digammaf_(0.5f * (nu + 1.f - (float)(d + 1))) - logf(Psi);
        }
        float elnpi = digammaf_(1.f + nj) - digammaf_(asum);
        logits[bc] = elnpi + 0.5f * elnlam;
    }
}

// ---------------- final: BN over batch per class + sigmoid ----------------
__global__ void k_final(const float* __restrict__ logits, float* __restrict__ out) {
    int c = blockIdx.x;
    int b = threadIdx.x;
    float v = logits[b * CC + c];
    float s = v, s2 = v * v;
#pragma unroll
    for (int o = 32; o > 0; o >>= 1) { s += __shfl_down(s, o); s2 += __shfl_down(s2, o); }
    __shared__ float ls[2], lq[2];
    int lane = b & 63, wid = b >> 6;
    if (lane == 0) { ls[wid] = s; lq[wid] = s2; }
    __syncthreads();
    float mu = (ls[0] + ls[1]) * (1.f / 128.f);
    float var = (lq[0] + lq[1]) * (1.f / 128.f) - mu * mu;
    out[b * CC + c] = 1.f / (1.f + expf(-(v - mu) * rsqrtf(var + 1e-5f)));
}

extern "C" void kernel_launch(void* const* d_in, const int* in_sizes, int n_in,
                              void* d_out, int out_size, void* d_ws, size_t ws_size,
                              hipStream_t stream) {
    (void)in_sizes; (void)n_in; (void)out_size; (void)ws_size;
    const float* x       = (const float*)d_in[0];
    const float* conv1_w = (const float*)d_in[1];
    const float* bn1_g   = (const float*)d_in[2];
    const float* bn1_b   = (const float*)d_in[3];
    const float* prim_w  = (const float*)d_in[4];
    const float* bna_g   = (const float*)d_in[5];
    const float* bna_b   = (const float*)d_in[6];
    const float* bnp_g   = (const float*)d_in[7];
    const float* bnp_b   = (const float*)d_in[8];
    const float* Wij     = (const float*)d_in[9];

    float* ws = (float*)d_ws;
    float* h   = ws;                                          // 3,211,264 f32
    float* pcT = ws + 3211264;                                // 2,506,752 f32 [4608][544]
    unsigned short* Bh = (unsigned short*)(ws + 5718016);     // 5,308,416 bf16
    unsigned short* Bl = (unsigned short*)(ws + 8372224);     // 5,308,416 bf16
    unsigned short* Ahp = (unsigned short*)(ws + 11026432);   //   663,552 bf16
    unsigned short* Alp = (unsigned short*)(ws + 11358208);   //   663,552 bf16
    float* S0a    = ws + 11690368;   // 2,560
    float* S1a    = ws + 11692928;   // 40,960
    float* S2a    = ws + 11733888;   // 40,960
    float* S0b    = ws + 11774848;   // 2,560
    float* S1b    = ws + 11777408;   // 40,960
    float* S2b    = ws + 11818368;   // 40,960
    float* logits = ws + 11859328;   // 1,280
    float* part1  = ws + 11860608;   // 2,048
    float* part2  = ws + 11862656;   //   640
    float* out    = (float*)d_out;

    k_conv1<<<dim3(7, 128), 256, 0, stream>>>(x, conv1_w, h);
    k_bnstats1a<<<1024, 256, 0, stream>>>(h, part1);
    k_pim<<<2916, 256, 0, stream>>>(prim_w, h, part1, bn1_g, bn1_b, Ahp, Alp, Bh, Bl);
    k_gemm<<<648, 256, 0, stream>>>(Ahp, Alp, Bh, Bl, pcT);
    k_bnstats2a<<<320, 256, 0, stream>>>(pcT, part2);

    // routing: iter0 (R = 1/C) -> A; iter1 (expect from A) -> B; iter2 (expect from B) -> A
    k_routed<1><<<256, 640, 0, stream>>>(pcT, part2, bna_g, bna_b, bnp_g, bnp_b, Wij,
                                         S0a, S1a, S2a, S0a, S1a, S2a);
    k_routed<0><<<256, 640, 0, stream>>>(pcT, part2, bna_g, bna_b, bnp_g, bnp_b, Wij,
                                         S0a, S1a, S2a, S0b, S1b, S2b);
    k_routed<0><<<256, 640, 0, stream>>>(pcT, part2, bna_g, bna_b, bnp_g, bnp_b, Wij,
                                         S0b, S1b, S2b, S0a, S1a, S2a);
    k_expect_final<<<128, 64, 0, stream>>>(S0a, S1a, S2a, logits);

    k_final<<<10, 128, 0, stream>>>(logits, out);
}